// Round 19
// baseline (543.080 us; speedup 1.0000x reference)
//
#include <hip/hip_runtime.h>
#include <math.h>

#define NTOK 577
#define NB 8
#define NC 1024
#define NH 16
#define HD 64
#define M_ROWS (NB*NTOK)               // 4616
#define SZ ((size_t)NB*NH*NTOK*HD)     // 4726784 elements
#define WSZ ((size_t)3*NC*NC)          // 3145728
#define PSZ ((size_t)NC*NC)            // 1048576
#define VTW 608                        // padded key width for VT (19*32)
#define VTSZ ((size_t)NB*NH*HD*VTW)    // 4980736
#define HSTR ((size_t)NTOK*HD)         // 36928 head stride in A-layout
#define LP 36                          // padded LDS row (32 data + 4 pad)
#define LOG2E 1.44269504088896f

typedef __attribute__((ext_vector_type(8)))  short bf16x8_t;
typedef __attribute__((ext_vector_type(8)))  unsigned short u16x8_t;
typedef __attribute__((ext_vector_type(16))) float f32x16_t;

union U4 { unsigned short s[8]; unsigned int u[4]; bf16x8_t v; };

__device__ inline unsigned short f2bf(float x){
    unsigned int u = __float_as_uint(x);
    u = (u + 0x7FFFu + ((u>>16)&1u)) >> 16;
    return (unsigned short)u;
}
__device__ inline float bf2f(unsigned short h){
    return __uint_as_float(((unsigned int)h)<<16);
}
__device__ inline unsigned int cvt_pk(float a, float b){
    unsigned int r;
    asm volatile("v_cvt_pk_bf16_f32 %0, %1, %2" : "=v"(r) : "v"(a), "v"(b));
    return r;
}
__device__ inline float fexp2(float x){
    float r;
    asm("v_exp_f32 %0, %1" : "=v"(r) : "v"(x));
    return r;
}

// ---------------------------------------------------------------------------
// merged split + fused row-norm:
// rows 0..4615: X gather -> (xh,xl) + rn; 4616..7687: qkv_w -> wh (hi);
// rows 7688..8711: proj_w -> ph (hi)
// ---------------------------------------------------------------------------
__global__ __launch_bounds__(256) void split_all(const float* __restrict__ X,
        const float* __restrict__ W, const float* __restrict__ P,
        unsigned short* __restrict__ xh, unsigned short* __restrict__ xl,
        unsigned short* __restrict__ wh, unsigned short* __restrict__ ph,
        float* __restrict__ rn)
{
    int row = blockIdx.x, t = threadIdx.x;
    if (row < M_ROWS){
        int b = row / NTOK, n = row % NTOK;
        const float* s = X + ((size_t)n*NB + b)*NC + 4*t;
        float4 v = *(const float4*)s;
        ushort4 hv, lv;
        hv.x = f2bf(v.x); lv.x = f2bf(v.x - bf2f(hv.x));
        hv.y = f2bf(v.y); lv.y = f2bf(v.y - bf2f(hv.y));
        hv.z = f2bf(v.z); lv.z = f2bf(v.z - bf2f(hv.z));
        hv.w = f2bf(v.w); lv.w = f2bf(v.w - bf2f(hv.w));
        *(ushort4*)(xh + (size_t)row*NC + 4*t) = hv;
        *(ushort4*)(xl + (size_t)row*NC + 4*t) = lv;
        float ss = v.x*v.x + v.y*v.y + v.z*v.z + v.w*v.w;
        #pragma unroll
        for (int o = 1; o < 64; o <<= 1) ss += __shfl_xor(ss, o);
        __shared__ float red[4];
        if ((t & 63) == 0) red[t >> 6] = ss;
        __syncthreads();
        if (t == 0) rn[row] = sqrtf(red[0] + red[1] + red[2] + red[3]);
    } else if (row < M_ROWS + 3*NC){
        size_t drow = row - M_ROWS;
        float4 v = *(const float4*)(W + drow*NC + 4*t);
        ushort4 hv;
        hv.x = f2bf(v.x); hv.y = f2bf(v.y); hv.z = f2bf(v.z); hv.w = f2bf(v.w);
        *(ushort4*)(wh + drow*NC + 4*t) = hv;
    } else {
        size_t drow = row - M_ROWS - 3*NC;
        float4 v = *(const float4*)(P + drow*NC + 4*t);
        ushort4 hv;
        hv.x = f2bf(v.x); hv.y = f2bf(v.y); hv.z = f2bf(v.z); hv.w = f2bf(v.w);
        *(ushort4*)(ph + drow*NC + 4*t) = hv;
    }
}

__global__ __launch_bounds__(256) void calc_invtemp(const float* __restrict__ rn,
                                                    float* __restrict__ it)
{
    int b = blockIdx.x;
    int tid = threadIdx.x;
    float s = 0.f;
    for (int i = tid; i < NTOK; i += 256) s += rn[b*NTOK + i];
    #pragma unroll
    for (int o = 1; o < 64; o <<= 1) s += __shfl_xor(s, o);
    __shared__ float red[4];
    if ((tid & 63) == 0) red[tid >> 6] = s;
    __syncthreads();
    if (tid == 0) it[b] = (red[0]+red[1]+red[2]+red[3]) / (float)NTOK * 0.125f;
}

// ---------------------------------------------------------------------------
// Coalesced transpose: src hi-bf16 [BH][577][64] -> dst [BH][64][608], pads=0.
// ---------------------------------------------------------------------------
__device__ __forceinline__ void transp_body(const unsigned short* src,
                                            unsigned short* dst)
{
    __shared__ unsigned short t[64][72];
    int bh = blockIdx.y;
    int n0 = blockIdx.x * 64;
    int tid = threadIdx.x;
    int r  = tid >> 2;
    int c0 = (tid & 3) * 16;
    int n = n0 + r;
    if (n < NTOK){
        const unsigned short* s = src + ((size_t)bh*NTOK + n)*HD + c0;
        *(u16x8_t*)&t[r][c0]   = *(const u16x8_t*)s;
        *(u16x8_t*)&t[r][c0+8] = *(const u16x8_t*)(s + 8);
    } else {
        u16x8_t z = (u16x8_t)0;
        *(u16x8_t*)&t[r][c0]   = z;
        *(u16x8_t*)&t[r][c0+8] = z;
    }
    __syncthreads();
    if (n0 + c0 < VTW){
        int d = r;
        U4 o0, o1;
        #pragma unroll
        for (int j = 0; j < 8; j++){ o0.s[j] = t[c0+j][d]; o1.s[j] = t[c0+8+j][d]; }
        unsigned short* dp = dst + ((size_t)bh*HD + d)*VTW + n0 + c0;
        *(u16x8_t*)dp       = (u16x8_t)o0.v;
        *(u16x8_t*)(dp + 8) = (u16x8_t)o1.v;
    }
}

__global__ __launch_bounds__(256) void transp64(const unsigned short* __restrict__ src,
                                                unsigned short* __restrict__ dst)
{
    transp_body(src, dst);
}

__global__ __launch_bounds__(256) void transp64x3(
    const unsigned short* __restrict__ s0, unsigned short* __restrict__ d0,
    const unsigned short* __restrict__ s1, unsigned short* __restrict__ d1,
    const unsigned short* __restrict__ s2, unsigned short* __restrict__ d2)
{
    int i = blockIdx.z;
    const unsigned short* s = (i == 0) ? s0 : (i == 1 ? s1 : s2);
    unsigned short* d = (i == 0) ? d0 : (i == 1 ? d1 : d2);
    transp_body(s, d);
}

// A split bf16x2, B hi-only: 8 MFMAs per kk (hh + lh)
#define MFMA8(a0h,a1h,b0,b1,a0l,a1l) \
    acc[0][0] = __builtin_amdgcn_mfma_f32_32x32x16_bf16(a0h, b0, acc[0][0], 0,0,0); \
    acc[0][1] = __builtin_amdgcn_mfma_f32_32x32x16_bf16(a0h, b1, acc[0][1], 0,0,0); \
    acc[1][0] = __builtin_amdgcn_mfma_f32_32x32x16_bf16(a1h, b0, acc[1][0], 0,0,0); \
    acc[1][1] = __builtin_amdgcn_mfma_f32_32x32x16_bf16(a1h, b1, acc[1][1], 0,0,0); \
    acc[0][0] = __builtin_amdgcn_mfma_f32_32x32x16_bf16(a0l, b0, acc[0][0], 0,0,0); \
    acc[0][1] = __builtin_amdgcn_mfma_f32_32x32x16_bf16(a0l, b1, acc[0][1], 0,0,0); \
    acc[1][0] = __builtin_amdgcn_mfma_f32_32x32x16_bf16(a1l, b0, acc[1][0], 0,0,0); \
    acc[1][1] = __builtin_amdgcn_mfma_f32_32x32x16_bf16(a1l, b1, acc[1][1], 0,0,0);

// ---------------------------------------------------------------------------
// qkv GEMM, LDS-staged (128x128 tile, BK=32). A = X split bf16x2, B = W hi.
// ---------------------------------------------------------------------------
__global__ __launch_bounds__(256) void gemm_qkv_mfma(
    const unsigned short* __restrict__ Ah, const unsigned short* __restrict__ Al,
    const unsigned short* __restrict__ Bh,
    const float* __restrict__ bias,
    unsigned short* __restrict__ qh, unsigned short* __restrict__ ql,
    unsigned short* __restrict__ kh, unsigned short* __restrict__ kl,
    unsigned short* __restrict__ vh, unsigned short* __restrict__ vl)
{
    __shared__ unsigned short ahs[128][LP], als[128][LP];
    __shared__ unsigned short bhs[128][LP];
    int t = threadIdx.x;
    int l = t & 63, w = t >> 6;
    int lq = l & 31, hi = l >> 5;
    int wr = w >> 1, wc = w & 1;
    int col0 = blockIdx.x*128, row0 = blockIdx.y*128;

    int srow[2], scol[2], sa[2];
    #pragma unroll
    for (int i = 0; i < 2; i++){
        int idx = i*256 + t;
        srow[i] = idx >> 2;
        scol[i] = (idx & 3) * 8;
        int ar = row0 + srow[i]; if (ar >= M_ROWS) ar = M_ROWS-1;
        sa[i] = ar;
    }

    f32x16_t acc[2][2];
    #pragma unroll
    for (int i = 0; i < 16; i++){
        acc[0][0][i]=0.f; acc[0][1][i]=0.f; acc[1][0][i]=0.f; acc[1][1][i]=0.f;
    }

    for (int k0 = 0; k0 < NC; k0 += 32){
        if (k0) __syncthreads();
        #pragma unroll
        for (int i = 0; i < 2; i++){
            size_t ao = (size_t)sa[i]*NC + k0 + scol[i];
            size_t bo = (size_t)(col0 + srow[i])*NC + k0 + scol[i];
            u16x8_t va  = *(const u16x8_t*)(Ah + ao);
            u16x8_t va2 = *(const u16x8_t*)(Al + ao);
            u16x8_t vb  = *(const u16x8_t*)(Bh + bo);
            *(u16x8_t*)&ahs[srow[i]][scol[i]] = va;
            *(u16x8_t*)&als[srow[i]][scol[i]] = va2;
            *(u16x8_t*)&bhs[srow[i]][scol[i]] = vb;
        }
        __syncthreads();
        #pragma unroll
        for (int kk = 0; kk < 2; kk++){
            int co = kk*16 + 8*hi;
            bf16x8_t a0h = *(const bf16x8_t*)&ahs[wr*64+lq][co];
            bf16x8_t a1h = *(const bf16x8_t*)&ahs[wr*64+32+lq][co];
            bf16x8_t b0  = *(const bf16x8_t*)&bhs[wc*64+lq][co];
            bf16x8_t b1  = *(const bf16x8_t*)&bhs[wc*64+32+lq][co];
            bf16x8_t a0l = *(const bf16x8_t*)&als[wr*64+lq][co];
            bf16x8_t a1l = *(const bf16x8_t*)&als[wr*64+32+lq][co];
            MFMA8(a0h,a1h,b0,b1,a0l,a1l)
        }
    }

    int colW = col0 + wc*64, rowW = row0 + wr*64;
    #pragma unroll
    for (int fn = 0; fn < 2; fn++){
        int colb = colW + fn*32 + lq;
        float bb = bias[colb];
        int tt = colb >> 10, h = (colb >> 6) & 15, d = colb & 63;
        unsigned short* dsth = (tt == 0) ? qh : (tt == 1 ? kh : vh);
        unsigned short* dstl = (tt == 0) ? ql : (tt == 1 ? kl : vl);
        #pragma unroll
        for (int fm = 0; fm < 2; fm++){
            #pragma unroll
            for (int r = 0; r < 16; r++){
                int orow = rowW + fm*32 + (r&3) + 8*(r>>2) + 4*hi;
                if (orow < M_ROWS){
                    float val = acc[fm][fn][r] + bb;
                    int b = orow / NTOK, n = orow % NTOK;
                    unsigned short hv = f2bf(val);
                    unsigned short lv = f2bf(val - bf2f(hv));
                    size_t idx = ((size_t)(b*NH + h)*NTOK + n)*HD + d;
                    dsth[idx] = hv; dstl[idx] = lv;
                }
            }
        }
    }
}

// ---------------------------------------------------------------------------
// proj GEMM body, LDS-staged (64x128 tile, BK=32). A split bf16x2 HEAD
// layout, B hi-only. NA=1 single A pair; NA=3 fused sum of 3 pairs.
// ---------------------------------------------------------------------------
template<int NA>
__device__ __forceinline__ void proj_body(
    const unsigned short* A0h, const unsigned short* A0l,
    const unsigned short* A1h, const unsigned short* A1l,
    const unsigned short* A2h, const unsigned short* A2l,
    const unsigned short* Bh,
    const float* bias, float alpha, float* out, int bx, int by)
{
    __shared__ unsigned short ahs[64][LP], als[64][LP];
    __shared__ unsigned short bhs[128][LP];
    int t = threadIdx.x;
    int l = t & 63, w = t >> 6;
    int lq = l & 31, hi = l >> 5;
    int wr = w >> 1, wc = w & 1;
    int col0 = bx*128, row0 = by*64;

    int sarow = t >> 2, sacol = (t & 3) * 8;
    int ar = row0 + sarow; if (ar >= M_ROWS) ar = M_ROWS-1;
    size_t abase = (size_t)(ar / NTOK)*NH*HSTR + (size_t)(ar % NTOK)*HD;
    int sbrow[2], sbcol[2];
    #pragma unroll
    for (int i = 0; i < 2; i++){
        int idx = i*256 + t;
        sbrow[i] = idx >> 2;
        sbcol[i] = (idx & 3) * 8;
    }

    f32x16_t acc[2];
    #pragma unroll
    for (int i = 0; i < 16; i++){ acc[0][i]=0.f; acc[1][i]=0.f; }

    for (int k0 = 0; k0 < NC; k0 += 32){
        if (k0) __syncthreads();
        {
            int kk = k0 + sacol;
            size_t ao = abase + (size_t)(kk >> 6)*HSTR + (kk & 63);
            U4 h0, l0;
            u16x8_t va  = *(const u16x8_t*)(A0h + ao);
            u16x8_t va2 = *(const u16x8_t*)(A0l + ao);
            if (NA == 3){
                u16x8_t vb  = *(const u16x8_t*)(A1h + ao);
                u16x8_t vb2 = *(const u16x8_t*)(A1l + ao);
                u16x8_t vc  = *(const u16x8_t*)(A2h + ao);
                u16x8_t vc2 = *(const u16x8_t*)(A2l + ao);
                #pragma unroll
                for (int j = 0; j < 8; j++){
                    float s = bf2f(va[j]) + bf2f(va2[j]) + bf2f(vb[j])
                            + bf2f(vb2[j]) + bf2f(vc[j]) + bf2f(vc2[j]);
                    unsigned short hv = f2bf(s);
                    h0.s[j] = hv; l0.s[j] = f2bf(s - bf2f(hv));
                }
                *(u16x8_t*)&ahs[sarow][sacol] = (u16x8_t)h0.v;
                *(u16x8_t*)&als[sarow][sacol] = (u16x8_t)l0.v;
            } else {
                *(u16x8_t*)&ahs[sarow][sacol] = va;
                *(u16x8_t*)&als[sarow][sacol] = va2;
            }
            #pragma unroll
            for (int i = 0; i < 2; i++){
                size_t bo = (size_t)(col0 + sbrow[i])*NC + k0 + sbcol[i];
                u16x8_t vb = *(const u16x8_t*)(Bh + bo);
                *(u16x8_t*)&bhs[sbrow[i]][sbcol[i]] = vb;
            }
        }
        __syncthreads();
        #pragma unroll
        for (int kk = 0; kk < 2; kk++){
            int co = kk*16 + 8*hi;
            bf16x8_t a0h = *(const bf16x8_t*)&ahs[wr*32+lq][co];
            bf16x8_t a0l = *(const bf16x8_t*)&als[wr*32+lq][co];
            bf16x8_t b0  = *(const bf16x8_t*)&bhs[wc*64+lq][co];
            bf16x8_t b1  = *(const bf16x8_t*)&bhs[wc*64+32+lq][co];
            acc[0] = __builtin_amdgcn_mfma_f32_32x32x16_bf16(a0h, b0, acc[0], 0,0,0);
            acc[1] = __builtin_amdgcn_mfma_f32_32x32x16_bf16(a0h, b1, acc[1], 0,0,0);
            acc[0] = __builtin_amdgcn_mfma_f32_32x32x16_bf16(a0l, b0, acc[0], 0,0,0);
            acc[1] = __builtin_amdgcn_mfma_f32_32x32x16_bf16(a0l, b1, acc[1], 0,0,0);
        }
    }

    #pragma unroll
    for (int fn = 0; fn < 2; fn++){
        int colb = col0 + wc*64 + fn*32 + lq;
        float bb = bias[colb];
        #pragma unroll
        for (int r = 0; r < 16; r++){
            int orow = row0 + wr*32 + (r&3) + 8*(r>>2) + 4*hi;
            if (orow < M_ROWS){
                int b = orow / NTOK, n = orow % NTOK;
                out[((size_t)n*NB + b)*NC + colb] = alpha*acc[fn][r] + bb;
            }
        }
    }
}

// 2-slice proj: z==0 -> x_gem (fused sum3), z==1 -> x_ori.
__global__ __launch_bounds__(256) void proj2(
    const unsigned short* __restrict__ A0h, const unsigned short* __restrict__ A0l,
    const unsigned short* __restrict__ A1h, const unsigned short* __restrict__ A1l,
    const unsigned short* __restrict__ A2h, const unsigned short* __restrict__ A2l,
    const unsigned short* __restrict__ Oh, const unsigned short* __restrict__ Ol,
    const unsigned short* __restrict__ Bh,
    const float* __restrict__ bias, float* __restrict__ out_gem,
    float* __restrict__ out_ori)
{
    if (blockIdx.z == 0)
        proj_body<3>(A0h,A0l,A1h,A1l,A2h,A2l,Bh,bias,1.f/3.f,out_gem,
                     blockIdx.x, blockIdx.y);
    else
        proj_body<1>(Oh,Ol,Oh,Ol,Oh,Ol,Bh,bias,1.f,out_ori,
                     blockIdx.x, blockIdx.y);
}

// ---------------------------------------------------------------------------
// Split-K flash: partial pass over kt in [kt0,kt1), hi-only scores,
// exp2-domain softmax. VAR=0 online (keeps m,l); VAR=1/2 static max.
// ---------------------------------------------------------------------------
template<int VAR>
__device__ __forceinline__ void flash_part(
    const unsigned short* Qh, const unsigned short* Kh,
    const unsigned short* VT, float l2s, int bh, int qt, int lane,
    int kt0, int kt1, f32x16_t& od0, f32x16_t& od1, float& m_, float& l_)
{
    int hi = lane >> 5, lq = lane & 31;
    const size_t base = (size_t)bh * NTOK * HD;
    const size_t vtb  = (size_t)bh * HD * VTW;

    int qrow = qt*32 + lq;
    int qr = qrow < NTOK ? qrow : NTOK-1;
    const size_t qoff = base + (size_t)qr*HD + 8*hi;
    bf16x8_t qfh[4];
    #pragma unroll
    for (int c = 0; c < 4; c++)
        qfh[c] = *(const bf16x8_t*)(Qh + qoff + 16*c);

    for (int kt = kt0; kt < kt1; kt++){
        int krow = kt*32 + lq;
        int kr = krow < NTOK ? krow : NTOK-1;
        const size_t koff = base + (size_t)kr*HD + 8*hi;
        bf16x8_t kfh[4];
        #pragma unroll
        for (int c = 0; c < 4; c++)
            kfh[c] = *(const bf16x8_t*)(Kh + koff + 16*c);
        f32x16_t sf;
        #pragma unroll
        for (int r = 0; r < 16; r++) sf[r] = 0.f;
        __builtin_amdgcn_s_setprio(1);
        #pragma unroll
        for (int c = 0; c < 4; c++)
            sf = __builtin_amdgcn_mfma_f32_32x32x16_bf16(kfh[c], qfh[c], sf, 0,0,0);
        __builtin_amdgcn_s_setprio(0);

        float p[16];
        if (VAR == 0){
            float tm = -1e30f;
            if (kt == 18){
                #pragma unroll
                for (int r = 0; r < 16; r++){
                    int key = 576 + (r&3) + 8*(r>>2) + 4*hi;
                    p[r] = (key < NTOK) ? sf[r]*l2s : -1e30f;
                    tm = fmaxf(tm, p[r]);
                }
            } else {
                #pragma unroll
                for (int r = 0; r < 16; r++){ p[r] = sf[r]*l2s; tm = fmaxf(tm, p[r]); }
            }
            tm = fmaxf(tm, __shfl_xor(tm, 32));
            float mn = fmaxf(m_, tm);
            float corr = fexp2(m_ - mn);
            float ps = 0.f;
            #pragma unroll
            for (int r = 0; r < 16; r++){ p[r] = fexp2(p[r] - mn); ps += p[r]; }
            ps += __shfl_xor(ps, 32);
            l_ = l_*corr + ps;
            m_ = mn;
            #pragma unroll
            for (int r = 0; r < 16; r++){
                int crow = (r&3) + 8*(r>>2) + 4*hi;
                float cR = __shfl(corr, crow);
                od0[r] *= cR; od1[r] *= cR;
            }
        } else {
            if (kt == 18){
                #pragma unroll
                for (int r = 0; r < 16; r++){
                    int key = 576 + (r&3) + 8*(r>>2) + 4*hi;
                    p[r] = (key < NTOK) ? fexp2(sf[r]*l2s - l2s) : 0.f;
                }
            } else {
                #pragma unroll
                for (int r = 0; r < 16; r++) p[r] = fexp2(sf[r]*l2s - l2s);
            }
            if (VAR == 2){
                #pragma unroll
                for (int r = 0; r < 16; r++) l_ += p[r];
            }
        }

        U4 pa[2];
        #pragma unroll
        for (int ks = 0; ks < 2; ks++){
            unsigned int X0 = cvt_pk(p[8*ks+0], p[8*ks+1]);
            unsigned int X1 = cvt_pk(p[8*ks+2], p[8*ks+3]);
            unsigned int X2 = cvt_pk(p[8*ks+4], p[8*ks+5]);
            unsigned int X3 = cvt_pk(p[8*ks+6], p[8*ks+7]);
            unsigned int Y0 = (unsigned int)__shfl_xor((int)X2, 32);
            unsigned int Y1 = (unsigned int)__shfl_xor((int)X3, 32);
            unsigned int Y2 = (unsigned int)__shfl_xor((int)X0, 32);
            unsigned int Y3 = (unsigned int)__shfl_xor((int)X1, 32);
            pa[ks].u[0] = hi ? Y0 : X0;
            pa[ks].u[1] = hi ? Y1 : X1;
            pa[ks].u[2] = hi ? X2 : Y2;
            pa[ks].u[3] = hi ? X3 : Y3;
        }
        const size_t v0 = vtb + (size_t)lq*VTW      + kt*32 + 8*hi;
        const size_t v1 = vtb + (size_t)(32+lq)*VTW + kt*32 + 8*hi;
        bf16x8_t vf00 = *(const bf16x8_t*)(VT + v0);
        bf16x8_t vf01 = *(const bf16x8_t*)(VT + v0 + 16);
        bf16x8_t vf10 = *(const bf16x8_t*)(VT + v1);
        bf16x8_t vf11 = *(const bf16x8_t*)(VT + v1 + 16);
        __builtin_amdgcn_s_setprio(1);
        od0 = __builtin_amdgcn_mfma_f32_32x32x16_bf16(pa[0].v, vf00, od0, 0,0,0);
        od0 = __builtin_amdgcn_mfma_f32_32x32x16_bf16(pa[1].v, vf01, od0, 0,0,0);
        od1 = __builtin_amdgcn_mfma_f32_32x32x16_bf16(pa[0].v, vf10, od1, 0,0,0);
        od1 = __builtin_amdgcn_mfma_f32_32x32x16_bf16(pa[1].v, vf11, od1, 0,0,0);
        __builtin_amdgcn_s_setprio(0);
    }
}

// Split-K driver: 512 threads; wave w<4 does kt 0-9 for q-tile w, wave w+4
// does kt 10-18; partner posts partials to LDS; lower wave merges + epilogue.
template<int VAR>
__device__ __forceinline__ void flash_split(
    const unsigned short* Qh, const unsigned short* Kh,
    const unsigned short* VT,
    unsigned short* Ohi, unsigned short* Olo,
    float scale, int bh, int qt, int tid, float (*part)[64][34])
{
    int w = tid >> 6, lane = tid & 63;
    int wq = w & 3, half = w >> 2;
    int hi = lane >> 5, lq = lane & 31;
    const size_t base = (size_t)bh * NTOK * HD;
    const float l2s = scale * LOG2E;

    f32x16_t od0, od1;
    #pragma unroll
    for (int r = 0; r < 16; r++){ od0[r]=0.f; od1[r]=0.f; }
    float m_ = -1e30f, l_ = 0.f;

    flash_part<VAR>(Qh, Kh, VT, l2s, bh, qt, lane,
                    half ? 10 : 0, half ? 19 : 10, od0, od1, m_, l_);

    if (half){
        float* dst = part[wq][lane];
        #pragma unroll
        for (int r = 0; r < 16; r++){ dst[r] = od0[r]; dst[16+r] = od1[r]; }
        dst[32] = m_; dst[33] = l_;
    }
    __syncthreads();
    if (half) return;

    const float* src = part[wq][lane];
    if (VAR == 0){
        float mB = src[32], lB = src[33];
        float mN = fmaxf(m_, mB);
        float cA = fexp2(m_ - mN), cB = fexp2(mB - mN);
        l_ = l_*cA + lB*cB;
        m_ = mN;
        #pragma unroll
        for (int r = 0; r < 16; r++){
            int crow = (r&3) + 8*(r>>2) + 4*hi;
            float a = __shfl(cA, crow), b = __shfl(cB, crow);
            od0[r] = od0[r]*a + src[r]*b;
            od1[r] = od1[r]*a + src[16+r]*b;
        }
    } else {
        if (VAR == 2) l_ += src[33];
        #pragma unroll
        for (int r = 0; r < 16; r++){
            od0[r] += src[r];
            od1[r] += src[16+r];
        }
    }

    if (VAR == 1){
        #pragma unroll
        for (int r = 0; r < 16; r++){
            float s = od0[r]*od0[r] + od1[r]*od1[r];
            #pragma unroll
            for (int o = 1; o < 32; o <<= 1) s += __shfl_xor(s, o);
            int crow = (r&3) + 8*(r>>2) + 4*hi;
            int qg = qt*32 + crow;
            if (qg < NTOK){
                float inv = 1.f / fmaxf(sqrtf(s), 1e-12f);
                size_t o0 = base + (size_t)qg*HD + lq;
                Ohi[o0]    = f2bf(od0[r]*inv);
                Ohi[o0+32] = f2bf(od1[r]*inv);
            }
        }
        return;
    }

    if (VAR == 2) l_ = l_ + __shfl_xor(l_, 32);
    float linv = 1.f / l_;
    #pragma unroll
    for (int r = 0; r < 16; r++){
        int crow = (r&3) + 8*(r>>2) + 4*hi;
        int qg = qt*32 + crow;
        float li = __shfl(linv, crow);
        if (qg < NTOK){
            size_t o0 = base + (size_t)qg*HD + lq;
            float a0 = od0[r]*li, a1 = od1[r]*li;
            unsigned short h0 = f2bf(a0), h1 = f2bf(a1);
            Ohi[o0] = h0;    Olo[o0]    = f2bf(a0 - bf2f(h0));
            Ohi[o0+32] = h1; Olo[o0+32] = f2bf(a1 - bf2f(h1));
        }
    }
}

// 4-wide merged ys+ori (split-K, 512 thr): slices 0-2 = ys_i (VAR=1, fused
// l2n, hi out); slice 3 = x_ori (VAR=0) -> o_ori split pair.
__global__ __launch_bounds__(512) void flash4s(
    const unsigned short* __restrict__ x1h,
    const unsigned short* __restrict__ x2h,
    const unsigned short* __restrict__ x3h,
    const unsigned short* __restrict__ qh_,
    const unsigned short* __restrict__ kh_,
    const unsigned short* __restrict__ vt1, const unsigned short* __restrict__ vt2,
    const unsigned short* __restrict__ vt3, const unsigned short* __restrict__ vtv,
    unsigned short* __restrict__ z1h,
    unsigned short* __restrict__ z2h,
    unsigned short* __restrict__ z3h,
    unsigned short* __restrict__ ooh, unsigned short* __restrict__ ool,
    const float* __restrict__ itemp)
{
    __shared__ float part[4][64][34];
    int bid = blockIdx.x;
    int bh = (bid & 7) * 16 + (bid >> 3) / 5;
    int tile = (bid >> 3) % 5;
    int wq = (threadIdx.x >> 6) & 3;
    int qt = tile*4 + wq; if (qt > 18) qt = 18;
    int i = blockIdx.y;
    if (i == 3){
        flash_split<0>(qh_, kh_, vtv, ooh, ool, 0.125f, bh, qt,
                       threadIdx.x, part);
    } else {
        const unsigned short *Qh, *VT;
        unsigned short *Oh;
        if (i == 0){ Qh=x1h; VT=vt1; Oh=z1h; }
        else if (i == 1){ Qh=x2h; VT=vt2; Oh=z2h; }
        else { Qh=x3h; VT=vt3; Oh=z3h; }
        flash_split<1>(Qh, Qh, VT, Oh, nullptr, itemp[bh >> 4], bh, qt,
                       threadIdx.x, part);
    }
}

// finals (split-K, 512 thr, 3 slices, VAR=2)
__global__ __launch_bounds__(512) void flashfin(
    const unsigned short* __restrict__ z1h,
    const unsigned short* __restrict__ z2h,
    const unsigned short* __restrict__ z3h,
    const unsigned short* __restrict__ vtv,
    unsigned short* __restrict__ o0h, unsigned short* __restrict__ o0l,
    unsigned short* __restrict__ o1h, unsigned short* __restrict__ o1l,
    unsigned short* __restrict__ o2h, unsigned short* __restrict__ o2l,
    const float* __restrict__ itemp)
{
    __shared__ float part[4][64][34];
    int bid = blockIdx.x;
    int bh = (bid & 7) * 16 + (bid >> 3) / 5;
    int tile = (bid >> 3) % 5;
    int wq = (threadIdx.x >> 6) & 3;
    int qt = tile*4 + wq; if (qt > 18) qt = 18;
    int i = blockIdx.y;
    const unsigned short* Qh;
    unsigned short *Oh, *Ol;
    if (i == 0){ Qh=z1h; Oh=o0h; Ol=o0l; }
    else if (i == 1){ Qh=z2h; Oh=o1h; Ol=o1l; }
    else { Qh=z3h; Oh=o2h; Ol=o2l; }
    flash_split<2>(Qh, Qh, vtv, Oh, Ol, itemp[bh >> 4], bh, qt,
                   threadIdx.x, part);
}

// ---------------------------------------------------------------------------
// 3-slice L2-normalize (rows of 64, split in -> split out). In-place safe.
// ---------------------------------------------------------------------------
__device__ __forceinline__ void l2n_body(const unsigned short* ih,
        const unsigned short* il, unsigned short* oh, unsigned short* ol)
{
    size_t row = (size_t)blockIdx.x*4 + (threadIdx.x >> 6);
    int lane = threadIdx.x & 63;
    size_t ii = row*HD + lane;
    float x = bf2f(ih[ii]) + bf2f(il[ii]);
    float s = x*x;
    #pragma unroll
    for (int o = 1; o < 64; o <<= 1) s += __shfl_xor(s, o);
    float xn = x / fmaxf(sqrtf(s), 1e-12f);
    unsigned short hv = f2bf(xn);
    oh[ii] = hv;
    ol[ii] = f2bf(xn - bf2f(hv));
}

__global__ __launch_bounds__(256) void l2n3(
    const unsigned short* __restrict__ i0h, const unsigned short* __restrict__ i0l,
    unsigned short* __restrict__ o0h, unsigned short* __restrict__ o0l,
    const unsigned short* __restrict__ i1h, const unsigned short* __restrict__ i1l,
    unsigned short* __restrict__ o1h, unsigned short* __restrict__ o1l,
    const unsigned short* __restrict__ i2h, const unsigned short* __restrict__ i2l,
    unsigned short* __restrict__ o2h, unsigned short* __restrict__ o2l)
{
    int i = blockIdx.y;
    if (i == 0) l2n_body(i0h, i0l, o0h, o0l);
    else if (i == 1) l2n_body(i1h, i1l, o1h, o1l);
    else l2n_body(i2h, i2l, o2h, o2l);
}

// ---------------------------------------------------------------------------
extern "C" void kernel_launch(void* const* d_in, const int* in_sizes, int n_in,
                              void* d_out, int out_size, void* d_ws, size_t ws_size,
                              hipStream_t stream)
{
    const float* x      = (const float*)d_in[0];
    const float* qkv_w  = (const float*)d_in[1];
    const float* qkv_b  = (const float*)d_in[2];
    const float* proj_w = (const float*)d_in[3];
    const float* proj_b = (const float*)d_in[4];
    float* out = (float*)d_out;            // [0,SZ)=x_gem, [SZ,2SZ)=x_ori

    unsigned short* w16 = (unsigned short*)d_ws;
    #define SL(i) (w16 + (size_t)(i)*SZ)          // 8 bf16 slots
    unsigned short* WQh = w16 + 8*SZ;             // WQ hi, dead after qkv
    unsigned short* VT1 = WQh;                    // aliases WQ
    size_t p = 8*SZ + 2*WSZ;
    unsigned short* VTv = w16 + p;  p += VTSZ;
    unsigned short* VT2 = w16 + p;  p += VTSZ;
    unsigned short* VT3 = w16 + p;  p += VTSZ;
    unsigned short* WPh = w16 + p;  p += PSZ;
    p += PSZ;                                     // layout keep
    unsigned short* E0  = w16 + p;  p += SZ;
    unsigned short* E1  = w16 + p;  p += SZ;
    float* rn = (float*)(w16 + p);  p += 2*(M_ROWS + 8);
    float* it = rn + M_ROWS;
    unsigned short* F0 = w16 + p;  p += SZ;
    unsigned short* F1 = w16 + p;  p += SZ;
    unsigned short* G0 = w16 + p;  p += SZ;
    p += SZ;

    dim3 blk(256), blk5(512);
    dim3 gq(24,37), gt(10,128), gt3(10,128,3), gl3(18464,3);
    dim3 gfl4(640,4), gfl3(640,3), gp2(8,73,2);

    // prologue: merged splits + fused row-norm, inv_temp, qkv gemm, VTv
    split_all<<<dim3(M_ROWS + 4*NC), blk, 0, stream>>>(x, qkv_w, proj_w,
        SL(6), SL(7), WQh, WPh, rn);
    calc_invtemp<<<dim3(NB), blk, 0, stream>>>(rn, it);
    gemm_qkv_mfma<<<gq, blk, 0, stream>>>(SL(6), SL(7), WQh, qkv_b,
        SL(0), SL(1), SL(2), SL(3), SL(4), SL(5));
    transp64<<<gt, blk, 0, stream>>>(SL(4), VTv);

    // xs1 = l2n(v) in-place (4,5); xs2 = l2n(k)->(6,7); xs3 = l2n(q)->E
    l2n3<<<gl3, blk, 0, stream>>>(
        SL(4),SL(5), SL(4),SL(5),
        SL(2),SL(3), SL(6),SL(7),
        SL(0),SL(1), E0,E1);
    transp64x3<<<gt3, blk, 0, stream>>>(SL(4), VT1, SL(6), VT2, E0, VT3);

    // merged split-K: z1->F0, z2->F1, z3->G0 (hi only); o_ori->(SL1,SL3)
    // (slice 3 reads SL0/SL2 hi only; their lo halves are dead -> safe dst)
    flash4s<<<gfl4, blk5, 0, stream>>>(
        SL(4), SL(6), E0,
        SL(0), SL(2),
        VT1, VT2, VT3, VTv,
        F0, F1, G0, SL(1), SL(3), it);

    // finals split-K: z x VTv -> (4,5),(6,7),(E0,E1) split
    flashfin<<<gfl3, blk5, 0, stream>>>(
        F0, F1, G0, VTv,
        SL(4),SL(5), SL(6),SL(7), E0,E1, it);

    // both projections in one dispatch (independent):
    // z=0: x_gem = proj(sum3/3); z=1: x_ori = proj(o_ori)
    proj2<<<gp2, blk, 0, stream>>>(
        SL(4),SL(5), SL(6),SL(7), E0,E1,
        SL(1),SL(3),
        WPh, proj_b, out, out + SZ);
    #undef SL
}

// Round 20
// 480.801 us; speedup vs baseline: 1.1295x; 1.1295x over previous
//
#include <hip/hip_runtime.h>
#include <math.h>

#define NTOK 577
#define NB 8
#define NC 1024
#define NH 16
#define HD 64
#define M_ROWS (NB*NTOK)               // 4616
#define SZ ((size_t)NB*NH*NTOK*HD)     // 4726784 elements
#define WSZ ((size_t)3*NC*NC)          // 3145728
#define PSZ ((size_t)NC*NC)            // 1048576
#define VTW 608                        // padded key width for VT (19*32)
#define VTSZ ((size_t)NB*NH*HD*VTW)    // 4980736
#define HSTR ((size_t)NTOK*HD)         // 36928 head stride in A-layout
#define LP 36                          // padded LDS row (32 data + 4 pad)
#define LOG2E 1.44269504088896f

typedef __attribute__((ext_vector_type(8)))  short bf16x8_t;
typedef __attribute__((ext_vector_type(8)))  unsigned short u16x8_t;
typedef __attribute__((ext_vector_type(16))) float f32x16_t;

union U4 { unsigned short s[8]; unsigned int u[4]; bf16x8_t v; };

__device__ inline unsigned short f2bf(float x){
    unsigned int u = __float_as_uint(x);
    u = (u + 0x7FFFu + ((u>>16)&1u)) >> 16;
    return (unsigned short)u;
}
__device__ inline float bf2f(unsigned short h){
    return __uint_as_float(((unsigned int)h)<<16);
}
__device__ inline unsigned int cvt_pk(float a, float b){
    unsigned int r;
    asm volatile("v_cvt_pk_bf16_f32 %0, %1, %2" : "=v"(r) : "v"(a), "v"(b));
    return r;
}
__device__ inline float fexp2(float x){
    float r;
    asm("v_exp_f32 %0, %1" : "=v"(r) : "v"(x));
    return r;
}

// ---------------------------------------------------------------------------
// merged split + fused row-norm:
// rows 0..4615: X gather -> (xh,xl) + rn; 4616..7687: qkv_w -> wh (hi);
// rows 7688..8711: proj_w -> ph (hi)
// ---------------------------------------------------------------------------
__global__ __launch_bounds__(256) void split_all(const float* __restrict__ X,
        const float* __restrict__ W, const float* __restrict__ P,
        unsigned short* __restrict__ xh, unsigned short* __restrict__ xl,
        unsigned short* __restrict__ wh, unsigned short* __restrict__ ph,
        float* __restrict__ rn)
{
    int row = blockIdx.x, t = threadIdx.x;
    if (row < M_ROWS){
        int b = row / NTOK, n = row % NTOK;
        const float* s = X + ((size_t)n*NB + b)*NC + 4*t;
        float4 v = *(const float4*)s;
        ushort4 hv, lv;
        hv.x = f2bf(v.x); lv.x = f2bf(v.x - bf2f(hv.x));
        hv.y = f2bf(v.y); lv.y = f2bf(v.y - bf2f(hv.y));
        hv.z = f2bf(v.z); lv.z = f2bf(v.z - bf2f(hv.z));
        hv.w = f2bf(v.w); lv.w = f2bf(v.w - bf2f(hv.w));
        *(ushort4*)(xh + (size_t)row*NC + 4*t) = hv;
        *(ushort4*)(xl + (size_t)row*NC + 4*t) = lv;
        float ss = v.x*v.x + v.y*v.y + v.z*v.z + v.w*v.w;
        #pragma unroll
        for (int o = 1; o < 64; o <<= 1) ss += __shfl_xor(ss, o);
        __shared__ float red[4];
        if ((t & 63) == 0) red[t >> 6] = ss;
        __syncthreads();
        if (t == 0) rn[row] = sqrtf(red[0] + red[1] + red[2] + red[3]);
    } else if (row < M_ROWS + 3*NC){
        size_t drow = row - M_ROWS;
        float4 v = *(const float4*)(W + drow*NC + 4*t);
        ushort4 hv;
        hv.x = f2bf(v.x); hv.y = f2bf(v.y); hv.z = f2bf(v.z); hv.w = f2bf(v.w);
        *(ushort4*)(wh + drow*NC + 4*t) = hv;
    } else {
        size_t drow = row - M_ROWS - 3*NC;
        float4 v = *(const float4*)(P + drow*NC + 4*t);
        ushort4 hv;
        hv.x = f2bf(v.x); hv.y = f2bf(v.y); hv.z = f2bf(v.z); hv.w = f2bf(v.w);
        *(ushort4*)(ph + drow*NC + 4*t) = hv;
    }
}

__global__ __launch_bounds__(256) void calc_invtemp(const float* __restrict__ rn,
                                                    float* __restrict__ it)
{
    int b = blockIdx.x;
    int tid = threadIdx.x;
    float s = 0.f;
    for (int i = tid; i < NTOK; i += 256) s += rn[b*NTOK + i];
    #pragma unroll
    for (int o = 1; o < 64; o <<= 1) s += __shfl_xor(s, o);
    __shared__ float red[4];
    if ((tid & 63) == 0) red[tid >> 6] = s;
    __syncthreads();
    if (tid == 0) it[b] = (red[0]+red[1]+red[2]+red[3]) / (float)NTOK * 0.125f;
}

// ---------------------------------------------------------------------------
// Coalesced transpose: src hi-bf16 [BH][577][64] -> dst [BH][64][608], pads=0.
// ---------------------------------------------------------------------------
__device__ __forceinline__ void transp_body(const unsigned short* src,
                                            unsigned short* dst)
{
    __shared__ unsigned short t[64][72];
    int bh = blockIdx.y;
    int n0 = blockIdx.x * 64;
    int tid = threadIdx.x;
    int r  = tid >> 2;
    int c0 = (tid & 3) * 16;
    int n = n0 + r;
    if (n < NTOK){
        const unsigned short* s = src + ((size_t)bh*NTOK + n)*HD + c0;
        *(u16x8_t*)&t[r][c0]   = *(const u16x8_t*)s;
        *(u16x8_t*)&t[r][c0+8] = *(const u16x8_t*)(s + 8);
    } else {
        u16x8_t z = (u16x8_t)0;
        *(u16x8_t*)&t[r][c0]   = z;
        *(u16x8_t*)&t[r][c0+8] = z;
    }
    __syncthreads();
    if (n0 + c0 < VTW){
        int d = r;
        U4 o0, o1;
        #pragma unroll
        for (int j = 0; j < 8; j++){ o0.s[j] = t[c0+j][d]; o1.s[j] = t[c0+8+j][d]; }
        unsigned short* dp = dst + ((size_t)bh*HD + d)*VTW + n0 + c0;
        *(u16x8_t*)dp       = (u16x8_t)o0.v;
        *(u16x8_t*)(dp + 8) = (u16x8_t)o1.v;
    }
}

__global__ __launch_bounds__(256) void transp64(const unsigned short* __restrict__ src,
                                                unsigned short* __restrict__ dst)
{
    transp_body(src, dst);
}

__global__ __launch_bounds__(256) void transp64x3(
    const unsigned short* __restrict__ s0, unsigned short* __restrict__ d0,
    const unsigned short* __restrict__ s1, unsigned short* __restrict__ d1,
    const unsigned short* __restrict__ s2, unsigned short* __restrict__ d2)
{
    int i = blockIdx.z;
    const unsigned short* s = (i == 0) ? s0 : (i == 1 ? s1 : s2);
    unsigned short* d = (i == 0) ? d0 : (i == 1 ? d1 : d2);
    transp_body(s, d);
}

// A split bf16x2, B hi-only: 8 MFMAs per kk (hh + lh)
#define MFMA8(a0h,a1h,b0,b1,a0l,a1l) \
    acc[0][0] = __builtin_amdgcn_mfma_f32_32x32x16_bf16(a0h, b0, acc[0][0], 0,0,0); \
    acc[0][1] = __builtin_amdgcn_mfma_f32_32x32x16_bf16(a0h, b1, acc[0][1], 0,0,0); \
    acc[1][0] = __builtin_amdgcn_mfma_f32_32x32x16_bf16(a1h, b0, acc[1][0], 0,0,0); \
    acc[1][1] = __builtin_amdgcn_mfma_f32_32x32x16_bf16(a1h, b1, acc[1][1], 0,0,0); \
    acc[0][0] = __builtin_amdgcn_mfma_f32_32x32x16_bf16(a0l, b0, acc[0][0], 0,0,0); \
    acc[0][1] = __builtin_amdgcn_mfma_f32_32x32x16_bf16(a0l, b1, acc[0][1], 0,0,0); \
    acc[1][0] = __builtin_amdgcn_mfma_f32_32x32x16_bf16(a1l, b0, acc[1][0], 0,0,0); \
    acc[1][1] = __builtin_amdgcn_mfma_f32_32x32x16_bf16(a1l, b1, acc[1][1], 0,0,0);

// ---------------------------------------------------------------------------
// qkv GEMM, LDS-staged (128x128 tile, BK=32). A = X split bf16x2, B = W hi.
// ---------------------------------------------------------------------------
__global__ __launch_bounds__(256) void gemm_qkv_mfma(
    const unsigned short* __restrict__ Ah, const unsigned short* __restrict__ Al,
    const unsigned short* __restrict__ Bh,
    const float* __restrict__ bias,
    unsigned short* __restrict__ qh, unsigned short* __restrict__ ql,
    unsigned short* __restrict__ kh, unsigned short* __restrict__ kl,
    unsigned short* __restrict__ vh, unsigned short* __restrict__ vl)
{
    __shared__ unsigned short ahs[128][LP], als[128][LP];
    __shared__ unsigned short bhs[128][LP];
    int t = threadIdx.x;
    int l = t & 63, w = t >> 6;
    int lq = l & 31, hi = l >> 5;
    int wr = w >> 1, wc = w & 1;
    int col0 = blockIdx.x*128, row0 = blockIdx.y*128;

    int srow[2], scol[2], sa[2];
    #pragma unroll
    for (int i = 0; i < 2; i++){
        int idx = i*256 + t;
        srow[i] = idx >> 2;
        scol[i] = (idx & 3) * 8;
        int ar = row0 + srow[i]; if (ar >= M_ROWS) ar = M_ROWS-1;
        sa[i] = ar;
    }

    f32x16_t acc[2][2];
    #pragma unroll
    for (int i = 0; i < 16; i++){
        acc[0][0][i]=0.f; acc[0][1][i]=0.f; acc[1][0][i]=0.f; acc[1][1][i]=0.f;
    }

    for (int k0 = 0; k0 < NC; k0 += 32){
        if (k0) __syncthreads();
        #pragma unroll
        for (int i = 0; i < 2; i++){
            size_t ao = (size_t)sa[i]*NC + k0 + scol[i];
            size_t bo = (size_t)(col0 + srow[i])*NC + k0 + scol[i];
            u16x8_t va  = *(const u16x8_t*)(Ah + ao);
            u16x8_t va2 = *(const u16x8_t*)(Al + ao);
            u16x8_t vb  = *(const u16x8_t*)(Bh + bo);
            *(u16x8_t*)&ahs[srow[i]][scol[i]] = va;
            *(u16x8_t*)&als[srow[i]][scol[i]] = va2;
            *(u16x8_t*)&bhs[srow[i]][scol[i]] = vb;
        }
        __syncthreads();
        #pragma unroll
        for (int kk = 0; kk < 2; kk++){
            int co = kk*16 + 8*hi;
            bf16x8_t a0h = *(const bf16x8_t*)&ahs[wr*64+lq][co];
            bf16x8_t a1h = *(const bf16x8_t*)&ahs[wr*64+32+lq][co];
            bf16x8_t b0  = *(const bf16x8_t*)&bhs[wc*64+lq][co];
            bf16x8_t b1  = *(const bf16x8_t*)&bhs[wc*64+32+lq][co];
            bf16x8_t a0l = *(const bf16x8_t*)&als[wr*64+lq][co];
            bf16x8_t a1l = *(const bf16x8_t*)&als[wr*64+32+lq][co];
            MFMA8(a0h,a1h,b0,b1,a0l,a1l)
        }
    }

    int colW = col0 + wc*64, rowW = row0 + wr*64;
    #pragma unroll
    for (int fn = 0; fn < 2; fn++){
        int colb = colW + fn*32 + lq;
        float bb = bias[colb];
        int tt = colb >> 10, h = (colb >> 6) & 15, d = colb & 63;
        unsigned short* dsth = (tt == 0) ? qh : (tt == 1 ? kh : vh);
        unsigned short* dstl = (tt == 0) ? ql : (tt == 1 ? kl : vl);
        #pragma unroll
        for (int fm = 0; fm < 2; fm++){
            #pragma unroll
            for (int r = 0; r < 16; r++){
                int orow = rowW + fm*32 + (r&3) + 8*(r>>2) + 4*hi;
                if (orow < M_ROWS){
                    float val = acc[fm][fn][r] + bb;
                    int b = orow / NTOK, n = orow % NTOK;
                    unsigned short hv = f2bf(val);
                    unsigned short lv = f2bf(val - bf2f(hv));
                    size_t idx = ((size_t)(b*NH + h)*NTOK + n)*HD + d;
                    dsth[idx] = hv; dstl[idx] = lv;
                }
            }
        }
    }
}

// ---------------------------------------------------------------------------
// proj GEMM body, LDS-staged (64x128 tile, BK=32). A split bf16x2 HEAD
// layout, B hi-only. NA=1 single A pair; NA=3 fused sum of 3 pairs.
// ---------------------------------------------------------------------------
template<int NA>
__device__ __forceinline__ void proj_body(
    const unsigned short* A0h, const unsigned short* A0l,
    const unsigned short* A1h, const unsigned short* A1l,
    const unsigned short* A2h, const unsigned short* A2l,
    const unsigned short* Bh,
    const float* bias, float alpha, float* out, int bx, int by)
{
    __shared__ unsigned short ahs[64][LP], als[64][LP];
    __shared__ unsigned short bhs[128][LP];
    int t = threadIdx.x;
    int l = t & 63, w = t >> 6;
    int lq = l & 31, hi = l >> 5;
    int wr = w >> 1, wc = w & 1;
    int col0 = bx*128, row0 = by*64;

    int sarow = t >> 2, sacol = (t & 3) * 8;
    int ar = row0 + sarow; if (ar >= M_ROWS) ar = M_ROWS-1;
    size_t abase = (size_t)(ar / NTOK)*NH*HSTR + (size_t)(ar % NTOK)*HD;
    int sbrow[2], sbcol[2];
    #pragma unroll
    for (int i = 0; i < 2; i++){
        int idx = i*256 + t;
        sbrow[i] = idx >> 2;
        sbcol[i] = (idx & 3) * 8;
    }

    f32x16_t acc[2];
    #pragma unroll
    for (int i = 0; i < 16; i++){ acc[0][i]=0.f; acc[1][i]=0.f; }

    for (int k0 = 0; k0 < NC; k0 += 32){
        if (k0) __syncthreads();
        {
            int kk = k0 + sacol;
            size_t ao = abase + (size_t)(kk >> 6)*HSTR + (kk & 63);
            U4 h0, l0;
            u16x8_t va  = *(const u16x8_t*)(A0h + ao);
            u16x8_t va2 = *(const u16x8_t*)(A0l + ao);
            if (NA == 3){
                u16x8_t vb  = *(const u16x8_t*)(A1h + ao);
                u16x8_t vb2 = *(const u16x8_t*)(A1l + ao);
                u16x8_t vc  = *(const u16x8_t*)(A2h + ao);
                u16x8_t vc2 = *(const u16x8_t*)(A2l + ao);
                #pragma unroll
                for (int j = 0; j < 8; j++){
                    float s = bf2f(va[j]) + bf2f(va2[j]) + bf2f(vb[j])
                            + bf2f(vb2[j]) + bf2f(vc[j]) + bf2f(vc2[j]);
                    unsigned short hv = f2bf(s);
                    h0.s[j] = hv; l0.s[j] = f2bf(s - bf2f(hv));
                }
                *(u16x8_t*)&ahs[sarow][sacol] = (u16x8_t)h0.v;
                *(u16x8_t*)&als[sarow][sacol] = (u16x8_t)l0.v;
            } else {
                *(u16x8_t*)&ahs[sarow][sacol] = va;
                *(u16x8_t*)&als[sarow][sacol] = va2;
            }
            #pragma unroll
            for (int i = 0; i < 2; i++){
                size_t bo = (size_t)(col0 + sbrow[i])*NC + k0 + sbcol[i];
                u16x8_t vb = *(const u16x8_t*)(Bh + bo);
                *(u16x8_t*)&bhs[sbrow[i]][sbcol[i]] = vb;
            }
        }
        __syncthreads();
        #pragma unroll
        for (int kk = 0; kk < 2; kk++){
            int co = kk*16 + 8*hi;
            bf16x8_t a0h = *(const bf16x8_t*)&ahs[wr*32+lq][co];
            bf16x8_t a0l = *(const bf16x8_t*)&als[wr*32+lq][co];
            bf16x8_t b0  = *(const bf16x8_t*)&bhs[wc*64+lq][co];
            bf16x8_t b1  = *(const bf16x8_t*)&bhs[wc*64+32+lq][co];
            acc[0] = __builtin_amdgcn_mfma_f32_32x32x16_bf16(a0h, b0, acc[0], 0,0,0);
            acc[1] = __builtin_amdgcn_mfma_f32_32x32x16_bf16(a0h, b1, acc[1], 0,0,0);
            acc[0] = __builtin_amdgcn_mfma_f32_32x32x16_bf16(a0l, b0, acc[0], 0,0,0);
            acc[1] = __builtin_amdgcn_mfma_f32_32x32x16_bf16(a0l, b1, acc[1], 0,0,0);
        }
    }

    #pragma unroll
    for (int fn = 0; fn < 2; fn++){
        int colb = col0 + wc*64 + fn*32 + lq;
        float bb = bias[colb];
        #pragma unroll
        for (int r = 0; r < 16; r++){
            int orow = row0 + wr*32 + (r&3) + 8*(r>>2) + 4*hi;
            if (orow < M_ROWS){
                int b = orow / NTOK, n = orow % NTOK;
                out[((size_t)n*NB + b)*NC + colb] = alpha*acc[fn][r] + bb;
            }
        }
    }
}

// 2-slice proj: z==0 -> x_gem (fused sum3), z==1 -> x_ori.
__global__ __launch_bounds__(256) void proj2(
    const unsigned short* __restrict__ A0h, const unsigned short* __restrict__ A0l,
    const unsigned short* __restrict__ A1h, const unsigned short* __restrict__ A1l,
    const unsigned short* __restrict__ A2h, const unsigned short* __restrict__ A2l,
    const unsigned short* __restrict__ Oh, const unsigned short* __restrict__ Ol,
    const unsigned short* __restrict__ Bh,
    const float* __restrict__ bias, float* __restrict__ out_gem,
    float* __restrict__ out_ori)
{
    if (blockIdx.z == 0)
        proj_body<3>(A0h,A0l,A1h,A1l,A2h,A2l,Bh,bias,1.f/3.f,out_gem,
                     blockIdx.x, blockIdx.y);
    else
        proj_body<1>(Oh,Ol,Oh,Ol,Oh,Ol,Bh,bias,1.f,out_ori,
                     blockIdx.x, blockIdx.y);
}

// ---------------------------------------------------------------------------
// 2-phase LDS-staged flash (256 thr, 4 waves share K/V tiles).
// K tile [32][128B] XOR-swizzled (row&7)<<4; V tile [64][64B] swz (row&3)<<4.
// Stage: issue 16B global loads at iteration top (regs), ds_write + barrier
// at bottom -> L2 latency hides under compute. Hi-only scores, exp2 softmax.
// VAR=0 online+1/l; VAR=1 static max + fused l2n (hi out); VAR=2 static+1/l.
// ---------------------------------------------------------------------------
__device__ __forceinline__ void stage_load(
    const unsigned short* Kh, const unsigned short* VT,
    size_t base, size_t vtb, int kt, int t, u16x8_t& rk, u16x8_t& rv)
{
    int krow = t >> 3, kslot = t & 7;
    int kr = kt*32 + krow; if (kr >= NTOK) kr = NTOK-1;
    rk = *(const u16x8_t*)(Kh + base + (size_t)kr*HD + kslot*8);
    int vrow = t >> 2, vslot = t & 3;
    rv = *(const u16x8_t*)(VT + vtb + (size_t)vrow*VTW + kt*32 + vslot*8);
}

__device__ __forceinline__ void stage_write(
    unsigned short* kbuf, unsigned short* vbuf, int t,
    const u16x8_t rk, const u16x8_t rv)
{
    int krow = t >> 3, kslot = t & 7;
    int kb = krow*128 + ((kslot*16) ^ ((krow & 7) << 4));
    *(u16x8_t*)((char*)kbuf + kb) = rk;
    int vrow = t >> 2, vslot = t & 3;
    int vb = vrow*64 + ((vslot*16) ^ ((vrow & 3) << 4));
    *(u16x8_t*)((char*)vbuf + vb) = rv;
}

template<int VAR>
__device__ __forceinline__ void flash_body2(
    const unsigned short* Qh, const unsigned short* Kh,
    const unsigned short* VT,
    unsigned short* Ohi, unsigned short* Olo,
    float scale, int bh, int qt, int tid,
    unsigned short (*kbufs)[2048], unsigned short (*vbufs)[2048])
{
    int lane = tid & 63;
    int hi = lane >> 5, lq = lane & 31;
    const size_t base = (size_t)bh * NTOK * HD;
    const size_t vtb  = (size_t)bh * HD * VTW;
    const float l2s = scale * LOG2E;

    int qrow = qt*32 + lq;
    int qr = qrow < NTOK ? qrow : NTOK-1;
    const size_t qoff = base + (size_t)qr*HD + 8*hi;
    bf16x8_t qfh[4];
    #pragma unroll
    for (int c = 0; c < 4; c++)
        qfh[c] = *(const bf16x8_t*)(Qh + qoff + 16*c);

    f32x16_t od0, od1;
    #pragma unroll
    for (int r = 0; r < 16; r++){ od0[r]=0.f; od1[r]=0.f; }
    float m_ = -1e30f, l_ = 0.f;

    u16x8_t rk, rv;
    stage_load(Kh, VT, base, vtb, 0, tid, rk, rv);
    stage_write(kbufs[0], vbufs[0], tid, rk, rv);
    __syncthreads();
    int cur = 0;

    for (int kt = 0; kt < 19; kt++){
        if (kt < 18) stage_load(Kh, VT, base, vtb, kt+1, tid, rk, rv);

        const char* kb = (const char*)kbufs[cur];
        const char* vb = (const char*)vbufs[cur];
        bf16x8_t kfh[4];
        #pragma unroll
        for (int c = 0; c < 4; c++)
            kfh[c] = *(const bf16x8_t*)(kb + lq*128 +
                        ((32*c + 16*hi) ^ ((lq & 7) << 4)));
        f32x16_t sf;
        #pragma unroll
        for (int r = 0; r < 16; r++) sf[r] = 0.f;
        __builtin_amdgcn_s_setprio(1);
        #pragma unroll
        for (int c = 0; c < 4; c++)
            sf = __builtin_amdgcn_mfma_f32_32x32x16_bf16(kfh[c], qfh[c], sf, 0,0,0);
        __builtin_amdgcn_s_setprio(0);

        float p[16];
        if (VAR == 0){
            float tm = -1e30f;
            if (kt == 18){
                #pragma unroll
                for (int r = 0; r < 16; r++){
                    int key = 576 + (r&3) + 8*(r>>2) + 4*hi;
                    p[r] = (key < NTOK) ? sf[r]*l2s : -1e30f;
                    tm = fmaxf(tm, p[r]);
                }
            } else {
                #pragma unroll
                for (int r = 0; r < 16; r++){ p[r] = sf[r]*l2s; tm = fmaxf(tm, p[r]); }
            }
            tm = fmaxf(tm, __shfl_xor(tm, 32));
            float mn = fmaxf(m_, tm);
            float corr = fexp2(m_ - mn);
            float ps = 0.f;
            #pragma unroll
            for (int r = 0; r < 16; r++){ p[r] = fexp2(p[r] - mn); ps += p[r]; }
            ps += __shfl_xor(ps, 32);
            l_ = l_*corr + ps;
            m_ = mn;
            #pragma unroll
            for (int r = 0; r < 16; r++){
                int crow = (r&3) + 8*(r>>2) + 4*hi;
                float cR = __shfl(corr, crow);
                od0[r] *= cR; od1[r] *= cR;
            }
        } else {
            if (kt == 18){
                #pragma unroll
                for (int r = 0; r < 16; r++){
                    int key = 576 + (r&3) + 8*(r>>2) + 4*hi;
                    p[r] = (key < NTOK) ? fexp2(sf[r]*l2s - l2s) : 0.f;
                }
            } else {
                #pragma unroll
                for (int r = 0; r < 16; r++) p[r] = fexp2(sf[r]*l2s - l2s);
            }
            if (VAR == 2){
                #pragma unroll
                for (int r = 0; r < 16; r++) l_ += p[r];
            }
        }

        U4 pa[2];
        #pragma unroll
        for (int ks = 0; ks < 2; ks++){
            unsigned int X0 = cvt_pk(p[8*ks+0], p[8*ks+1]);
            unsigned int X1 = cvt_pk(p[8*ks+2], p[8*ks+3]);
            unsigned int X2 = cvt_pk(p[8*ks+4], p[8*ks+5]);
            unsigned int X3 = cvt_pk(p[8*ks+6], p[8*ks+7]);
            unsigned int Y0 = (unsigned int)__shfl_xor((int)X2, 32);
            unsigned int Y1 = (unsigned int)__shfl_xor((int)X3, 32);
            unsigned int Y2 = (unsigned int)__shfl_xor((int)X0, 32);
            unsigned int Y3 = (unsigned int)__shfl_xor((int)X1, 32);
            pa[ks].u[0] = hi ? Y0 : X0;
            pa[ks].u[1] = hi ? Y1 : X1;
            pa[ks].u[2] = hi ? X2 : Y2;
            pa[ks].u[3] = hi ? X3 : Y3;
        }
        int vsw = (lq & 3) << 4;
        bf16x8_t vf00 = *(const bf16x8_t*)(vb + lq*64      + ((16*hi)      ^ vsw));
        bf16x8_t vf01 = *(const bf16x8_t*)(vb + lq*64      + ((32 + 16*hi) ^ vsw));
        bf16x8_t vf10 = *(const bf16x8_t*)(vb + (32+lq)*64 + ((16*hi)      ^ vsw));
        bf16x8_t vf11 = *(const bf16x8_t*)(vb + (32+lq)*64 + ((32 + 16*hi) ^ vsw));
        __builtin_amdgcn_s_setprio(1);
        od0 = __builtin_amdgcn_mfma_f32_32x32x16_bf16(pa[0].v, vf00, od0, 0,0,0);
        od0 = __builtin_amdgcn_mfma_f32_32x32x16_bf16(pa[1].v, vf01, od0, 0,0,0);
        od1 = __builtin_amdgcn_mfma_f32_32x32x16_bf16(pa[0].v, vf10, od1, 0,0,0);
        od1 = __builtin_amdgcn_mfma_f32_32x32x16_bf16(pa[1].v, vf11, od1, 0,0,0);
        __builtin_amdgcn_s_setprio(0);

        if (kt < 18) stage_write(kbufs[cur^1], vbufs[cur^1], tid, rk, rv);
        __syncthreads();
        cur ^= 1;
    }

    if (VAR == 1){
        #pragma unroll
        for (int r = 0; r < 16; r++){
            float s = od0[r]*od0[r] + od1[r]*od1[r];
            #pragma unroll
            for (int o = 1; o < 32; o <<= 1) s += __shfl_xor(s, o);
            int crow = (r&3) + 8*(r>>2) + 4*hi;
            int qg = qt*32 + crow;
            if (qg < NTOK){
                float inv = 1.f / fmaxf(sqrtf(s), 1e-12f);
                size_t o0 = base + (size_t)qg*HD + lq;
                Ohi[o0]    = f2bf(od0[r]*inv);
                Ohi[o0+32] = f2bf(od1[r]*inv);
            }
        }
        return;
    }

    if (VAR == 2) l_ = l_ + __shfl_xor(l_, 32);
    float linv = 1.f / l_;
    #pragma unroll
    for (int r = 0; r < 16; r++){
        int crow = (r&3) + 8*(r>>2) + 4*hi;
        int qg = qt*32 + crow;
        float li = __shfl(linv, crow);
        if (qg < NTOK){
            size_t o0 = base + (size_t)qg*HD + lq;
            float a0 = od0[r]*li, a1 = od1[r]*li;
            unsigned short h0 = f2bf(a0), h1 = f2bf(a1);
            Ohi[o0] = h0;    Olo[o0]    = f2bf(a0 - bf2f(h0));
            Ohi[o0+32] = h1; Olo[o0+32] = f2bf(a1 - bf2f(h1));
        }
    }
}

// 4-wide merged ys+ori: slices 0-2 = ys_i (VAR=1, fused l2n, hi out);
// slice 3 = x_ori (VAR=0) -> o_ori split pair.
__global__ __launch_bounds__(256) void flash4(
    const unsigned short* __restrict__ x1h,
    const unsigned short* __restrict__ x2h,
    const unsigned short* __restrict__ x3h,
    const unsigned short* __restrict__ qh_,
    const unsigned short* __restrict__ kh_,
    const unsigned short* __restrict__ vt1, const unsigned short* __restrict__ vt2,
    const unsigned short* __restrict__ vt3, const unsigned short* __restrict__ vtv,
    unsigned short* __restrict__ z1h,
    unsigned short* __restrict__ z2h,
    unsigned short* __restrict__ z3h,
    unsigned short* __restrict__ ooh, unsigned short* __restrict__ ool,
    const float* __restrict__ itemp)
{
    __shared__ unsigned short kbufs[2][2048], vbufs[2][2048];
    int bid = blockIdx.x;
    int bh = (bid & 7) * 16 + (bid >> 3) / 5;
    int w = threadIdx.x >> 6;
    int qt = ((bid >> 3) % 5) * 4 + w; if (qt > 18) qt = 18;
    int i = blockIdx.y;
    if (i == 3){
        flash_body2<0>(qh_, kh_, vtv, ooh, ool, 0.125f, bh, qt,
                       threadIdx.x, kbufs, vbufs);
    } else {
        const unsigned short *Qh, *VT;
        unsigned short *Oh;
        if (i == 0){ Qh=x1h; VT=vt1; Oh=z1h; }
        else if (i == 1){ Qh=x2h; VT=vt2; Oh=z2h; }
        else { Qh=x3h; VT=vt3; Oh=z3h; }
        flash_body2<1>(Qh, Qh, VT, Oh, nullptr, itemp[bh >> 4], bh, qt,
                       threadIdx.x, kbufs, vbufs);
    }
}

// finals (3 slices, VAR=2)
__global__ __launch_bounds__(256) void flashfin(
    const unsigned short* __restrict__ z1h,
    const unsigned short* __restrict__ z2h,
    const unsigned short* __restrict__ z3h,
    const unsigned short* __restrict__ vtv,
    unsigned short* __restrict__ o0h, unsigned short* __restrict__ o0l,
    unsigned short* __restrict__ o1h, unsigned short* __restrict__ o1l,
    unsigned short* __restrict__ o2h, unsigned short* __restrict__ o2l,
    const float* __restrict__ itemp)
{
    __shared__ unsigned short kbufs[2][2048], vbufs[2][2048];
    int bid = blockIdx.x;
    int bh = (bid & 7) * 16 + (bid >> 3) / 5;
    int w = threadIdx.x >> 6;
    int qt = ((bid >> 3) % 5) * 4 + w; if (qt > 18) qt = 18;
    int i = blockIdx.y;
    const unsigned short* Qh;
    unsigned short *Oh, *Ol;
    if (i == 0){ Qh=z1h; Oh=o0h; Ol=o0l; }
    else if (i == 1){ Qh=z2h; Oh=o1h; Ol=o1l; }
    else { Qh=z3h; Oh=o2h; Ol=o2l; }
    flash_body2<2>(Qh, Qh, vtv, Oh, Ol, itemp[bh >> 4], bh, qt,
                   threadIdx.x, kbufs, vbufs);
}

// ---------------------------------------------------------------------------
// 3-slice L2-normalize (rows of 64, split in -> split out). In-place safe.
// ---------------------------------------------------------------------------
__device__ __forceinline__ void l2n_body(const unsigned short* ih,
        const unsigned short* il, unsigned short* oh, unsigned short* ol)
{
    size_t row = (size_t)blockIdx.x*4 + (threadIdx.x >> 6);
    int lane = threadIdx.x & 63;
    size_t ii = row*HD + lane;
    float x = bf2f(ih[ii]) + bf2f(il[ii]);
    float s = x*x;
    #pragma unroll
    for (int o = 1; o < 64; o <<= 1) s += __shfl_xor(s, o);
    float xn = x / fmaxf(sqrtf(s), 1e-12f);
    unsigned short hv = f2bf(xn);
    oh[ii] = hv;
    ol[ii] = f2bf(xn - bf2f(hv));
}

__global__ __launch_bounds__(256) void l2n3(
    const unsigned short* __restrict__ i0h, const unsigned short* __restrict__ i0l,
    unsigned short* __restrict__ o0h, unsigned short* __restrict__ o0l,
    const unsigned short* __restrict__ i1h, const unsigned short* __restrict__ i1l,
    unsigned short* __restrict__ o1h, unsigned short* __restrict__ o1l,
    const unsigned short* __restrict__ i2h, const unsigned short* __restrict__ i2l,
    unsigned short* __restrict__ o2h, unsigned short* __restrict__ o2l)
{
    int i = blockIdx.y;
    if (i == 0) l2n_body(i0h, i0l, o0h, o0l);
    else if (i == 1) l2n_body(i1h, i1l, o1h, o1l);
    else l2n_body(i2h, i2l, o2h, o2l);
}

// ---------------------------------------------------------------------------
extern "C" void kernel_launch(void* const* d_in, const int* in_sizes, int n_in,
                              void* d_out, int out_size, void* d_ws, size_t ws_size,
                              hipStream_t stream)
{
    const float* x      = (const float*)d_in[0];
    const float* qkv_w  = (const float*)d_in[1];
    const float* qkv_b  = (const float*)d_in[2];
    const float* proj_w = (const float*)d_in[3];
    const float* proj_b = (const float*)d_in[4];
    float* out = (float*)d_out;            // [0,SZ)=x_gem, [SZ,2SZ)=x_ori

    unsigned short* w16 = (unsigned short*)d_ws;
    #define SL(i) (w16 + (size_t)(i)*SZ)          // 8 bf16 slots
    unsigned short* WQh = w16 + 8*SZ;             // WQ hi, dead after qkv
    unsigned short* VT1 = WQh;                    // aliases WQ
    size_t p = 8*SZ + 2*WSZ;
    unsigned short* VTv = w16 + p;  p += VTSZ;
    unsigned short* VT2 = w16 + p;  p += VTSZ;
    unsigned short* VT3 = w16 + p;  p += VTSZ;
    unsigned short* WPh = w16 + p;  p += PSZ;
    p += PSZ;                                     // layout keep
    unsigned short* E0  = w16 + p;  p += SZ;
    unsigned short* E1  = w16 + p;  p += SZ;
    float* rn = (float*)(w16 + p);  p += 2*(M_ROWS + 8);
    float* it = rn + M_ROWS;
    unsigned short* F0 = w16 + p;  p += SZ;
    unsigned short* F1 = w16 + p;  p += SZ;
    unsigned short* G0 = w16 + p;  p += SZ;
    p += SZ;

    dim3 blk(256);
    dim3 gq(24,37), gt(10,128), gt3(10,128,3), gl3(18464,3);
    dim3 gfl4(640,4), gfl3(640,3), gp2(8,73,2);

    // prologue: merged splits + fused row-norm, inv_temp, qkv gemm, VTv
    split_all<<<dim3(M_ROWS + 4*NC), blk, 0, stream>>>(x, qkv_w, proj_w,
        SL(6), SL(7), WQh, WPh, rn);
    calc_invtemp<<<dim3(NB), blk, 0, stream>>>(rn, it);
    gemm_qkv_mfma<<<gq, blk, 0, stream>>>(SL(6), SL(7), WQh, qkv_b,
        SL(0), SL(1), SL(2), SL(3), SL(4), SL(5));
    transp64<<<gt, blk, 0, stream>>>(SL(4), VTv);

    // xs1 = l2n(v) in-place (4,5); xs2 = l2n(k)->(6,7); xs3 = l2n(q)->E
    l2n3<<<gl3, blk, 0, stream>>>(
        SL(4),SL(5), SL(4),SL(5),
        SL(2),SL(3), SL(6),SL(7),
        SL(0),SL(1), E0,E1);
    transp64x3<<<gt3, blk, 0, stream>>>(SL(4), VT1, SL(6), VT2, E0, VT3);

    // merged: z1->F0, z2->F1, z3->G0 (hi only); o_ori->(SL1,SL3)
    flash4<<<gfl4, blk, 0, stream>>>(
        SL(4), SL(6), E0,
        SL(0), SL(2),
        VT1, VT2, VT3, VTv,
        F0, F1, G0, SL(1), SL(3), it);

    // finals: z x VTv -> (4,5),(6,7),(E0,E1) split
    flashfin<<<gfl3, blk, 0, stream>>>(
        F0, F1, G0, VTv,
        SL(4),SL(5), SL(6),SL(7), E0,E1, it);

    // both projections in one dispatch (independent):
    // z=0: x_gem = proj(sum3/3); z=1: x_ori = proj(o_ori)
    proj2<<<gp2, blk, 0, stream>>>(
        SL(4),SL(5), SL(6),SL(7), E0,E1,
        SL(1),SL(3),
        WPh, proj_b, out, out + SZ);
    #undef SL
}

// Round 21
// 454.408 us; speedup vs baseline: 1.1951x; 1.0581x over previous
//
#include <hip/hip_runtime.h>
#include <math.h>

#define NTOK 577
#define NB 8
#define NC 1024
#define NH 16
#define HD 64
#define M_ROWS (NB*NTOK)               // 4616
#define SZ ((size_t)NB*NH*NTOK*HD)     // 4726784 elements
#define WSZ ((size_t)3*NC*NC)          // 3145728
#define PSZ ((size_t)NC*NC)            // 1048576
#define VTW 608                        // padded key width for VT (19*32)
#define VTSZ ((size_t)NB*NH*HD*VTW)    // 4980736
#define HSTR ((size_t)NTOK*HD)         // 36928 head stride in A-layout
#define LP 36                          // padded LDS row (32 data + 4 pad)
#define LOG2E 1.44269504088896f

typedef __attribute__((ext_vector_type(8)))  short bf16x8_t;
typedef __attribute__((ext_vector_type(8)))  unsigned short u16x8_t;
typedef __attribute__((ext_vector_type(16))) float f32x16_t;

union U4 { unsigned short s[8]; unsigned int u[4]; bf16x8_t v; };

__device__ inline unsigned short f2bf(float x){
    unsigned int u = __float_as_uint(x);
    u = (u + 0x7FFFu + ((u>>16)&1u)) >> 16;
    return (unsigned short)u;
}
__device__ inline float bf2f(unsigned short h){
    return __uint_as_float(((unsigned int)h)<<16);
}
__device__ inline unsigned int cvt_pk(float a, float b){
    unsigned int r;
    asm volatile("v_cvt_pk_bf16_f32 %0, %1, %2" : "=v"(r) : "v"(a), "v"(b));
    return r;
}
__device__ inline float fexp2(float x){
    float r;
    asm("v_exp_f32 %0, %1" : "=v"(r) : "v"(x));
    return r;
}

// ---------------------------------------------------------------------------
// merged split + fused row-norm.
// ---------------------------------------------------------------------------
__global__ __launch_bounds__(256) void split_all(const float* __restrict__ X,
        const float* __restrict__ W, const float* __restrict__ P,
        unsigned short* __restrict__ xh, unsigned short* __restrict__ xl,
        unsigned short* __restrict__ wh, unsigned short* __restrict__ ph,
        float* __restrict__ rn)
{
    int row = blockIdx.x, t = threadIdx.x;
    if (row < M_ROWS){
        int b = row / NTOK, n = row % NTOK;
        const float* s = X + ((size_t)n*NB + b)*NC + 4*t;
        float4 v = *(const float4*)s;
        ushort4 hv, lv;
        hv.x = f2bf(v.x); lv.x = f2bf(v.x - bf2f(hv.x));
        hv.y = f2bf(v.y); lv.y = f2bf(v.y - bf2f(hv.y));
        hv.z = f2bf(v.z); lv.z = f2bf(v.z - bf2f(hv.z));
        hv.w = f2bf(v.w); lv.w = f2bf(v.w - bf2f(hv.w));
        *(ushort4*)(xh + (size_t)row*NC + 4*t) = hv;
        *(ushort4*)(xl + (size_t)row*NC + 4*t) = lv;
        float ss = v.x*v.x + v.y*v.y + v.z*v.z + v.w*v.w;
        #pragma unroll
        for (int o = 1; o < 64; o <<= 1) ss += __shfl_xor(ss, o);
        __shared__ float red[4];
        if ((t & 63) == 0) red[t >> 6] = ss;
        __syncthreads();
        if (t == 0) rn[row] = sqrtf(red[0] + red[1] + red[2] + red[3]);
    } else if (row < M_ROWS + 3*NC){
        size_t drow = row - M_ROWS;
        float4 v = *(const float4*)(W + drow*NC + 4*t);
        ushort4 hv;
        hv.x = f2bf(v.x); hv.y = f2bf(v.y); hv.z = f2bf(v.z); hv.w = f2bf(v.w);
        *(ushort4*)(wh + drow*NC + 4*t) = hv;
    } else {
        size_t drow = row - M_ROWS - 3*NC;
        float4 v = *(const float4*)(P + drow*NC + 4*t);
        ushort4 hv;
        hv.x = f2bf(v.x); hv.y = f2bf(v.y); hv.z = f2bf(v.z); hv.w = f2bf(v.w);
        *(ushort4*)(ph + drow*NC + 4*t) = hv;
    }
}

__global__ __launch_bounds__(256) void calc_invtemp(const float* __restrict__ rn,
                                                    float* __restrict__ it)
{
    int b = blockIdx.x;
    int tid = threadIdx.x;
    float s = 0.f;
    for (int i = tid; i < NTOK; i += 256) s += rn[b*NTOK + i];
    #pragma unroll
    for (int o = 1; o < 64; o <<= 1) s += __shfl_xor(s, o);
    __shared__ float red[4];
    if ((tid & 63) == 0) red[tid >> 6] = s;
    __syncthreads();
    if (tid == 0) it[b] = (red[0]+red[1]+red[2]+red[3]) / (float)NTOK * 0.125f;
}

// ---------------------------------------------------------------------------
// Coalesced transpose: src hi-bf16 [BH][577][64] -> dst [BH][64][608], pads=0.
// ---------------------------------------------------------------------------
__device__ __forceinline__ void transp_body(const unsigned short* src,
                                            unsigned short* dst)
{
    __shared__ unsigned short t[64][72];
    int bh = blockIdx.y;
    int n0 = blockIdx.x * 64;
    int tid = threadIdx.x;
    int r  = tid >> 2;
    int c0 = (tid & 3) * 16;
    int n = n0 + r;
    if (n < NTOK){
        const unsigned short* s = src + ((size_t)bh*NTOK + n)*HD + c0;
        *(u16x8_t*)&t[r][c0]   = *(const u16x8_t*)s;
        *(u16x8_t*)&t[r][c0+8] = *(const u16x8_t*)(s + 8);
    } else {
        u16x8_t z = (u16x8_t)0;
        *(u16x8_t*)&t[r][c0]   = z;
        *(u16x8_t*)&t[r][c0+8] = z;
    }
    __syncthreads();
    if (n0 + c0 < VTW){
        int d = r;
        U4 o0, o1;
        #pragma unroll
        for (int j = 0; j < 8; j++){ o0.s[j] = t[c0+j][d]; o1.s[j] = t[c0+8+j][d]; }
        unsigned short* dp = dst + ((size_t)bh*HD + d)*VTW + n0 + c0;
        *(u16x8_t*)dp       = (u16x8_t)o0.v;
        *(u16x8_t*)(dp + 8) = (u16x8_t)o1.v;
    }
}

__global__ __launch_bounds__(256) void transp64(const unsigned short* __restrict__ src,
                                                unsigned short* __restrict__ dst)
{
    transp_body(src, dst);
}

__global__ __launch_bounds__(256) void transp64x3(
    const unsigned short* __restrict__ s0, unsigned short* __restrict__ d0,
    const unsigned short* __restrict__ s1, unsigned short* __restrict__ d1,
    const unsigned short* __restrict__ s2, unsigned short* __restrict__ d2)
{
    int i = blockIdx.z;
    const unsigned short* s = (i == 0) ? s0 : (i == 1 ? s1 : s2);
    unsigned short* d = (i == 0) ? d0 : (i == 1 ? d1 : d2);
    transp_body(s, d);
}

// A split bf16x2, B hi-only: 8 MFMAs per kk (hh + lh)
#define MFMA8(a0h,a1h,b0,b1,a0l,a1l) \
    acc[0][0] = __builtin_amdgcn_mfma_f32_32x32x16_bf16(a0h, b0, acc[0][0], 0,0,0); \
    acc[0][1] = __builtin_amdgcn_mfma_f32_32x32x16_bf16(a0h, b1, acc[0][1], 0,0,0); \
    acc[1][0] = __builtin_amdgcn_mfma_f32_32x32x16_bf16(a1h, b0, acc[1][0], 0,0,0); \
    acc[1][1] = __builtin_amdgcn_mfma_f32_32x32x16_bf16(a1h, b1, acc[1][1], 0,0,0); \
    acc[0][0] = __builtin_amdgcn_mfma_f32_32x32x16_bf16(a0l, b0, acc[0][0], 0,0,0); \
    acc[0][1] = __builtin_amdgcn_mfma_f32_32x32x16_bf16(a0l, b1, acc[0][1], 0,0,0); \
    acc[1][0] = __builtin_amdgcn_mfma_f32_32x32x16_bf16(a1l, b0, acc[1][0], 0,0,0); \
    acc[1][1] = __builtin_amdgcn_mfma_f32_32x32x16_bf16(a1l, b1, acc[1][1], 0,0,0);

// ---------------------------------------------------------------------------
// qkv GEMM, LDS-staged (128x128 tile, BK=32). A = X split bf16x2, B = W hi.
// ---------------------------------------------------------------------------
__global__ __launch_bounds__(256) void gemm_qkv_mfma(
    const unsigned short* __restrict__ Ah, const unsigned short* __restrict__ Al,
    const unsigned short* __restrict__ Bh,
    const float* __restrict__ bias,
    unsigned short* __restrict__ qh, unsigned short* __restrict__ ql,
    unsigned short* __restrict__ kh, unsigned short* __restrict__ kl,
    unsigned short* __restrict__ vh, unsigned short* __restrict__ vl)
{
    __shared__ unsigned short ahs[128][LP], als[128][LP];
    __shared__ unsigned short bhs[128][LP];
    int t = threadIdx.x;
    int l = t & 63, w = t >> 6;
    int lq = l & 31, hi = l >> 5;
    int wr = w >> 1, wc = w & 1;
    int col0 = blockIdx.x*128, row0 = blockIdx.y*128;

    int srow[2], scol[2], sa[2];
    #pragma unroll
    for (int i = 0; i < 2; i++){
        int idx = i*256 + t;
        srow[i] = idx >> 2;
        scol[i] = (idx & 3) * 8;
        int ar = row0 + srow[i]; if (ar >= M_ROWS) ar = M_ROWS-1;
        sa[i] = ar;
    }

    f32x16_t acc[2][2];
    #pragma unroll
    for (int i = 0; i < 16; i++){
        acc[0][0][i]=0.f; acc[0][1][i]=0.f; acc[1][0][i]=0.f; acc[1][1][i]=0.f;
    }

    for (int k0 = 0; k0 < NC; k0 += 32){
        if (k0) __syncthreads();
        #pragma unroll
        for (int i = 0; i < 2; i++){
            size_t ao = (size_t)sa[i]*NC + k0 + scol[i];
            size_t bo = (size_t)(col0 + srow[i])*NC + k0 + scol[i];
            u16x8_t va  = *(const u16x8_t*)(Ah + ao);
            u16x8_t va2 = *(const u16x8_t*)(Al + ao);
            u16x8_t vb  = *(const u16x8_t*)(Bh + bo);
            *(u16x8_t*)&ahs[srow[i]][scol[i]] = va;
            *(u16x8_t*)&als[srow[i]][scol[i]] = va2;
            *(u16x8_t*)&bhs[srow[i]][scol[i]] = vb;
        }
        __syncthreads();
        #pragma unroll
        for (int kk = 0; kk < 2; kk++){
            int co = kk*16 + 8*hi;
            bf16x8_t a0h = *(const bf16x8_t*)&ahs[wr*64+lq][co];
            bf16x8_t a1h = *(const bf16x8_t*)&ahs[wr*64+32+lq][co];
            bf16x8_t b0  = *(const bf16x8_t*)&bhs[wc*64+lq][co];
            bf16x8_t b1  = *(const bf16x8_t*)&bhs[wc*64+32+lq][co];
            bf16x8_t a0l = *(const bf16x8_t*)&als[wr*64+lq][co];
            bf16x8_t a1l = *(const bf16x8_t*)&als[wr*64+32+lq][co];
            MFMA8(a0h,a1h,b0,b1,a0l,a1l)
        }
    }

    int colW = col0 + wc*64, rowW = row0 + wr*64;
    #pragma unroll
    for (int fn = 0; fn < 2; fn++){
        int colb = colW + fn*32 + lq;
        float bb = bias[colb];
        int tt = colb >> 10, h = (colb >> 6) & 15, d = colb & 63;
        unsigned short* dsth = (tt == 0) ? qh : (tt == 1 ? kh : vh);
        unsigned short* dstl = (tt == 0) ? ql : (tt == 1 ? kl : vl);
        #pragma unroll
        for (int fm = 0; fm < 2; fm++){
            #pragma unroll
            for (int r = 0; r < 16; r++){
                int orow = rowW + fm*32 + (r&3) + 8*(r>>2) + 4*hi;
                if (orow < M_ROWS){
                    float val = acc[fm][fn][r] + bb;
                    int b = orow / NTOK, n = orow % NTOK;
                    unsigned short hv = f2bf(val);
                    unsigned short lv = f2bf(val - bf2f(hv));
                    size_t idx = ((size_t)(b*NH + h)*NTOK + n)*HD + d;
                    dsth[idx] = hv; dstl[idx] = lv;
                }
            }
        }
    }
}

// ---------------------------------------------------------------------------
// proj GEMM body, LDS-staged (64x128 tile, BK=32).
// ---------------------------------------------------------------------------
template<int NA>
__device__ __forceinline__ void proj_body(
    const unsigned short* A0h, const unsigned short* A0l,
    const unsigned short* A1h, const unsigned short* A1l,
    const unsigned short* A2h, const unsigned short* A2l,
    const unsigned short* Bh,
    const float* bias, float alpha, float* out, int bx, int by)
{
    __shared__ unsigned short ahs[64][LP], als[64][LP];
    __shared__ unsigned short bhs[128][LP];
    int t = threadIdx.x;
    int l = t & 63, w = t >> 6;
    int lq = l & 31, hi = l >> 5;
    int wr = w >> 1, wc = w & 1;
    int col0 = bx*128, row0 = by*64;

    int sarow = t >> 2, sacol = (t & 3) * 8;
    int ar = row0 + sarow; if (ar >= M_ROWS) ar = M_ROWS-1;
    size_t abase = (size_t)(ar / NTOK)*NH*HSTR + (size_t)(ar % NTOK)*HD;
    int sbrow[2], sbcol[2];
    #pragma unroll
    for (int i = 0; i < 2; i++){
        int idx = i*256 + t;
        sbrow[i] = idx >> 2;
        sbcol[i] = (idx & 3) * 8;
    }

    f32x16_t acc[2];
    #pragma unroll
    for (int i = 0; i < 16; i++){ acc[0][i]=0.f; acc[1][i]=0.f; }

    for (int k0 = 0; k0 < NC; k0 += 32){
        if (k0) __syncthreads();
        {
            int kk = k0 + sacol;
            size_t ao = abase + (size_t)(kk >> 6)*HSTR + (kk & 63);
            U4 h0, l0;
            u16x8_t va  = *(const u16x8_t*)(A0h + ao);
            u16x8_t va2 = *(const u16x8_t*)(A0l + ao);
            if (NA == 3){
                u16x8_t vb  = *(const u16x8_t*)(A1h + ao);
                u16x8_t vb2 = *(const u16x8_t*)(A1l + ao);
                u16x8_t vc  = *(const u16x8_t*)(A2h + ao);
                u16x8_t vc2 = *(const u16x8_t*)(A2l + ao);
                #pragma unroll
                for (int j = 0; j < 8; j++){
                    float s = bf2f(va[j]) + bf2f(va2[j]) + bf2f(vb[j])
                            + bf2f(vb2[j]) + bf2f(vc[j]) + bf2f(vc2[j]);
                    unsigned short hv = f2bf(s);
                    h0.s[j] = hv; l0.s[j] = f2bf(s - bf2f(hv));
                }
                *(u16x8_t*)&ahs[sarow][sacol] = (u16x8_t)h0.v;
                *(u16x8_t*)&als[sarow][sacol] = (u16x8_t)l0.v;
            } else {
                *(u16x8_t*)&ahs[sarow][sacol] = va;
                *(u16x8_t*)&als[sarow][sacol] = va2;
            }
            #pragma unroll
            for (int i = 0; i < 2; i++){
                size_t bo = (size_t)(col0 + sbrow[i])*NC + k0 + sbcol[i];
                u16x8_t vb = *(const u16x8_t*)(Bh + bo);
                *(u16x8_t*)&bhs[sbrow[i]][sbcol[i]] = vb;
            }
        }
        __syncthreads();
        #pragma unroll
        for (int kk = 0; kk < 2; kk++){
            int co = kk*16 + 8*hi;
            bf16x8_t a0h = *(const bf16x8_t*)&ahs[wr*32+lq][co];
            bf16x8_t a0l = *(const bf16x8_t*)&als[wr*32+lq][co];
            bf16x8_t b0  = *(const bf16x8_t*)&bhs[wc*64+lq][co];
            bf16x8_t b1  = *(const bf16x8_t*)&bhs[wc*64+32+lq][co];
            acc[0] = __builtin_amdgcn_mfma_f32_32x32x16_bf16(a0h, b0, acc[0], 0,0,0);
            acc[1] = __builtin_amdgcn_mfma_f32_32x32x16_bf16(a0h, b1, acc[1], 0,0,0);
            acc[0] = __builtin_amdgcn_mfma_f32_32x32x16_bf16(a0l, b0, acc[0], 0,0,0);
            acc[1] = __builtin_amdgcn_mfma_f32_32x32x16_bf16(a0l, b1, acc[1], 0,0,0);
        }
    }

    #pragma unroll
    for (int fn = 0; fn < 2; fn++){
        int colb = col0 + wc*64 + fn*32 + lq;
        float bb = bias[colb];
        #pragma unroll
        for (int r = 0; r < 16; r++){
            int orow = row0 + wr*32 + (r&3) + 8*(r>>2) + 4*hi;
            if (orow < M_ROWS){
                int b = orow / NTOK, n = orow % NTOK;
                out[((size_t)n*NB + b)*NC + colb] = alpha*acc[fn][r] + bb;
            }
        }
    }
}

// 2-slice proj: z==0 -> x_gem (fused sum3), z==1 -> x_ori.
__global__ __launch_bounds__(256) void proj2(
    const unsigned short* __restrict__ A0h, const unsigned short* __restrict__ A0l,
    const unsigned short* __restrict__ A1h, const unsigned short* __restrict__ A1l,
    const unsigned short* __restrict__ A2h, const unsigned short* __restrict__ A2l,
    const unsigned short* __restrict__ Oh, const unsigned short* __restrict__ Ol,
    const unsigned short* __restrict__ Bh,
    const float* __restrict__ bias, float* __restrict__ out_gem,
    float* __restrict__ out_ori)
{
    if (blockIdx.z == 0)
        proj_body<3>(A0h,A0l,A1h,A1l,A2h,A2l,Bh,bias,1.f/3.f,out_gem,
                     blockIdx.x, blockIdx.y);
    else
        proj_body<1>(Oh,Ol,Oh,Ol,Oh,Ol,Bh,bias,1.f,out_ori,
                     blockIdx.x, blockIdx.y);
}

// ---------------------------------------------------------------------------
// 2-phase LDS-staged flash, 2-kt unroll (pair ping-pong, 1 barrier / 2 kt).
// K tile [32][128B] XOR-swz (row&7)<<4; V tile [64][64B] swz (row&3)<<4.
// Hi-only scores, exp2 softmax. VAR=0 online+defer-max(THR=8)+1/l;
// VAR=1 static max + fused l2n (hi out); VAR=2 static+1/l.
// ---------------------------------------------------------------------------
__device__ __forceinline__ void stage_load(
    const unsigned short* Kh, const unsigned short* VT,
    size_t base, size_t vtb, int kt, int t, u16x8_t& rk, u16x8_t& rv)
{
    int krow = t >> 3, kslot = t & 7;
    int kr = kt*32 + krow; if (kr >= NTOK) kr = NTOK-1;
    rk = *(const u16x8_t*)(Kh + base + (size_t)kr*HD + kslot*8);
    int vrow = t >> 2, vslot = t & 3;
    int vc = kt*32; if (vc > VTW-32) vc = VTW-32;
    rv = *(const u16x8_t*)(VT + vtb + (size_t)vrow*VTW + vc + vslot*8);
}

__device__ __forceinline__ void stage_write(
    unsigned short* kbuf, unsigned short* vbuf, int t,
    const u16x8_t rk, const u16x8_t rv)
{
    int krow = t >> 3, kslot = t & 7;
    int kb = krow*128 + ((kslot*16) ^ ((krow & 7) << 4));
    *(u16x8_t*)((char*)kbuf + kb) = rk;
    int vrow = t >> 2, vslot = t & 3;
    int vb = vrow*64 + ((vslot*16) ^ ((vrow & 3) << 4));
    *(u16x8_t*)((char*)vbuf + vb) = rv;
}

// per-kt compute on a staged tile
template<int VAR>
__device__ __forceinline__ void flash_tile(
    const unsigned short* kbuf, const unsigned short* vbuf,
    int kt, const bf16x8_t* qfh, float l2s, int hi, int lq,
    f32x16_t& od0, f32x16_t& od1, float& m_, float& l_)
{
    const char* kb = (const char*)kbuf;
    const char* vb = (const char*)vbuf;
    bf16x8_t kfh[4];
    #pragma unroll
    for (int c = 0; c < 4; c++)
        kfh[c] = *(const bf16x8_t*)(kb + lq*128 +
                    ((32*c + 16*hi) ^ ((lq & 7) << 4)));
    f32x16_t sf;
    #pragma unroll
    for (int r = 0; r < 16; r++) sf[r] = 0.f;
    __builtin_amdgcn_s_setprio(1);
    #pragma unroll
    for (int c = 0; c < 4; c++)
        sf = __builtin_amdgcn_mfma_f32_32x32x16_bf16(kfh[c], qfh[c], sf, 0,0,0);
    __builtin_amdgcn_s_setprio(0);

    float p[16];
    if (VAR == 0){
        float tm = -1e30f;
        if (kt == 18){
            #pragma unroll
            for (int r = 0; r < 16; r++){
                int key = 576 + (r&3) + 8*(r>>2) + 4*hi;
                p[r] = (key < NTOK) ? sf[r]*l2s : -1e30f;
                tm = fmaxf(tm, p[r]);
            }
        } else {
            #pragma unroll
            for (int r = 0; r < 16; r++){ p[r] = sf[r]*l2s; tm = fmaxf(tm, p[r]); }
        }
        tm = fmaxf(tm, __shfl_xor(tm, 32));
        // defer-max (T13): rescale only if tile max exceeds m_ + 8
        if (!__all(tm <= m_ + 8.f)){
            float mn = fmaxf(m_, tm);
            float corr = fexp2(m_ - mn);
            l_ *= corr;
            m_ = mn;
            #pragma unroll
            for (int r = 0; r < 16; r++){
                int crow = (r&3) + 8*(r>>2) + 4*hi;
                float cR = __shfl(corr, crow);
                od0[r] *= cR; od1[r] *= cR;
            }
        }
        float ps = 0.f;
        #pragma unroll
        for (int r = 0; r < 16; r++){ p[r] = fexp2(p[r] - m_); ps += p[r]; }
        ps += __shfl_xor(ps, 32);
        l_ += ps;
    } else {
        if (kt == 18){
            #pragma unroll
            for (int r = 0; r < 16; r++){
                int key = 576 + (r&3) + 8*(r>>2) + 4*hi;
                p[r] = (key < NTOK) ? fexp2(sf[r]*l2s - l2s) : 0.f;
            }
        } else {
            #pragma unroll
            for (int r = 0; r < 16; r++) p[r] = fexp2(sf[r]*l2s - l2s);
        }
        if (VAR == 2){
            #pragma unroll
            for (int r = 0; r < 16; r++) l_ += p[r];
        }
    }

    U4 pa[2];
    #pragma unroll
    for (int ks = 0; ks < 2; ks++){
        unsigned int X0 = cvt_pk(p[8*ks+0], p[8*ks+1]);
        unsigned int X1 = cvt_pk(p[8*ks+2], p[8*ks+3]);
        unsigned int X2 = cvt_pk(p[8*ks+4], p[8*ks+5]);
        unsigned int X3 = cvt_pk(p[8*ks+6], p[8*ks+7]);
        unsigned int Y0 = (unsigned int)__shfl_xor((int)X2, 32);
        unsigned int Y1 = (unsigned int)__shfl_xor((int)X3, 32);
        unsigned int Y2 = (unsigned int)__shfl_xor((int)X0, 32);
        unsigned int Y3 = (unsigned int)__shfl_xor((int)X1, 32);
        pa[ks].u[0] = hi ? Y0 : X0;
        pa[ks].u[1] = hi ? Y1 : X1;
        pa[ks].u[2] = hi ? X2 : Y2;
        pa[ks].u[3] = hi ? X3 : Y3;
    }
    int vsw = (lq & 3) << 4;
    bf16x8_t vf00 = *(const bf16x8_t*)(vb + lq*64      + ((16*hi)      ^ vsw));
    bf16x8_t vf01 = *(const bf16x8_t*)(vb + lq*64      + ((32 + 16*hi) ^ vsw));
    bf16x8_t vf10 = *(const bf16x8_t*)(vb + (32+lq)*64 + ((16*hi)      ^ vsw));
    bf16x8_t vf11 = *(const bf16x8_t*)(vb + (32+lq)*64 + ((32 + 16*hi) ^ vsw));
    __builtin_amdgcn_s_setprio(1);
    od0 = __builtin_amdgcn_mfma_f32_32x32x16_bf16(pa[0].v, vf00, od0, 0,0,0);
    od0 = __builtin_amdgcn_mfma_f32_32x32x16_bf16(pa[1].v, vf01, od0, 0,0,0);
    od1 = __builtin_amdgcn_mfma_f32_32x32x16_bf16(pa[0].v, vf10, od1, 0,0,0);
    od1 = __builtin_amdgcn_mfma_f32_32x32x16_bf16(pa[1].v, vf11, od1, 0,0,0);
    __builtin_amdgcn_s_setprio(0);
}

template<int VAR>
__device__ __forceinline__ void flash_body2(
    const unsigned short* Qh, const unsigned short* Kh,
    const unsigned short* VT,
    unsigned short* Ohi, unsigned short* Olo,
    float scale, int bh, int qt, int tid,
    unsigned short (*kbufs)[2][2048], unsigned short (*vbufs)[2][2048])
{
    int lane = tid & 63;
    int hi = lane >> 5, lq = lane & 31;
    const size_t base = (size_t)bh * NTOK * HD;
    const size_t vtb  = (size_t)bh * HD * VTW;
    const float l2s = scale * LOG2E;

    int qrow = qt*32 + lq;
    int qr = qrow < NTOK ? qrow : NTOK-1;
    const size_t qoff = base + (size_t)qr*HD + 8*hi;
    bf16x8_t qfh[4];
    #pragma unroll
    for (int c = 0; c < 4; c++)
        qfh[c] = *(const bf16x8_t*)(Qh + qoff + 16*c);

    f32x16_t od0, od1;
    #pragma unroll
    for (int r = 0; r < 16; r++){ od0[r]=0.f; od1[r]=0.f; }
    float m_ = -1e30f, l_ = 0.f;

    u16x8_t rk0, rv0, rk1, rv1;
    stage_load(Kh, VT, base, vtb, 0, tid, rk0, rv0);
    stage_load(Kh, VT, base, vtb, 1, tid, rk1, rv1);
    stage_write(kbufs[0][0], vbufs[0][0], tid, rk0, rv0);
    stage_write(kbufs[0][1], vbufs[0][1], tid, rk1, rv1);
    __syncthreads();
    int cur = 0;

    for (int i = 0; i < 10; i++){
        int kt0 = 2*i;
        if (i < 9){
            stage_load(Kh, VT, base, vtb, kt0+2, tid, rk0, rv0);
            stage_load(Kh, VT, base, vtb, kt0+3, tid, rk1, rv1);
        }
        flash_tile<VAR>(kbufs[cur][0], vbufs[cur][0], kt0, qfh, l2s, hi, lq,
                        od0, od1, m_, l_);
        if (i < 9){
            stage_write(kbufs[cur^1][0], vbufs[cur^1][0], tid, rk0, rv0);
            stage_write(kbufs[cur^1][1], vbufs[cur^1][1], tid, rk1, rv1);
        }
        if (kt0 + 1 < 19)
            flash_tile<VAR>(kbufs[cur][1], vbufs[cur][1], kt0+1, qfh, l2s, hi, lq,
                            od0, od1, m_, l_);
        __syncthreads();
        cur ^= 1;
    }

    if (VAR == 1){
        #pragma unroll
        for (int r = 0; r < 16; r++){
            float s = od0[r]*od0[r] + od1[r]*od1[r];
            #pragma unroll
            for (int o = 1; o < 32; o <<= 1) s += __shfl_xor(s, o);
            int crow = (r&3) + 8*(r>>2) + 4*hi;
            int qg = qt*32 + crow;
            if (qg < NTOK){
                float inv = 1.f / fmaxf(sqrtf(s), 1e-12f);
                size_t o0 = base + (size_t)qg*HD + lq;
                Ohi[o0]    = f2bf(od0[r]*inv);
                Ohi[o0+32] = f2bf(od1[r]*inv);
            }
        }
        return;
    }

    if (VAR == 2) l_ = l_ + __shfl_xor(l_, 32);
    float linv = 1.f / l_;
    #pragma unroll
    for (int r = 0; r < 16; r++){
        int crow = (r&3) + 8*(r>>2) + 4*hi;
        int qg = qt*32 + crow;
        float li = __shfl(linv, crow);
        if (qg < NTOK){
            size_t o0 = base + (size_t)qg*HD + lq;
            float a0 = od0[r]*li, a1 = od1[r]*li;
            unsigned short h0 = f2bf(a0), h1 = f2bf(a1);
            Ohi[o0] = h0;    Olo[o0]    = f2bf(a0 - bf2f(h0));
            Ohi[o0+32] = h1; Olo[o0+32] = f2bf(a1 - bf2f(h1));
        }
    }
}

// 4-wide merged ys+ori: slices 0-2 = ys_i (VAR=1, fused l2n, hi out);
// slice 3 = x_ori (VAR=0) -> o_ori split pair.
__global__ __launch_bounds__(256) void flash4(
    const unsigned short* __restrict__ x1h,
    const unsigned short* __restrict__ x2h,
    const unsigned short* __restrict__ x3h,
    const unsigned short* __restrict__ qh_,
    const unsigned short* __restrict__ kh_,
    const unsigned short* __restrict__ vt1, const unsigned short* __restrict__ vt2,
    const unsigned short* __restrict__ vt3, const unsigned short* __restrict__ vtv,
    unsigned short* __restrict__ z1h,
    unsigned short* __restrict__ z2h,
    unsigned short* __restrict__ z3h,
    unsigned short* __restrict__ ooh, unsigned short* __restrict__ ool,
    const float* __restrict__ itemp)
{
    __shared__ unsigned short kbufs[2][2][2048], vbufs[2][2][2048];
    int bid = blockIdx.x;
    int bh = (bid & 7) * 16 + (bid >> 3) / 5;
    int w = threadIdx.x >> 6;
    int qt = ((bid >> 3) % 5) * 4 + w; if (qt > 18) qt = 18;
    int i = blockIdx.y;
    if (i == 3){
        flash_body2<0>(qh_, kh_, vtv, ooh, ool, 0.125f, bh, qt,
                       threadIdx.x, kbufs, vbufs);
    } else {
        const unsigned short *Qh, *VT;
        unsigned short *Oh;
        if (i == 0){ Qh=x1h; VT=vt1; Oh=z1h; }
        else if (i == 1){ Qh=x2h; VT=vt2; Oh=z2h; }
        else { Qh=x3h; VT=vt3; Oh=z3h; }
        flash_body2<1>(Qh, Qh, VT, Oh, nullptr, itemp[bh >> 4], bh, qt,
                       threadIdx.x, kbufs, vbufs);
    }
}

// finals (3 slices, VAR=2)
__global__ __launch_bounds__(256) void flashfin(
    const unsigned short* __restrict__ z1h,
    const unsigned short* __restrict__ z2h,
    const unsigned short* __restrict__ z3h,
    const unsigned short* __restrict__ vtv,
    unsigned short* __restrict__ o0h, unsigned short* __restrict__ o0l,
    unsigned short* __restrict__ o1h, unsigned short* __restrict__ o1l,
    unsigned short* __restrict__ o2h, unsigned short* __restrict__ o2l,
    const float* __restrict__ itemp)
{
    __shared__ unsigned short kbufs[2][2][2048], vbufs[2][2][2048];
    int bid = blockIdx.x;
    int bh = (bid & 7) * 16 + (bid >> 3) / 5;
    int w = threadIdx.x >> 6;
    int qt = ((bid >> 3) % 5) * 4 + w; if (qt > 18) qt = 18;
    int i = blockIdx.y;
    const unsigned short* Qh;
    unsigned short *Oh, *Ol;
    if (i == 0){ Qh=z1h; Oh=o0h; Ol=o0l; }
    else if (i == 1){ Qh=z2h; Oh=o1h; Ol=o1l; }
    else { Qh=z3h; Oh=o2h; Ol=o2l; }
    flash_body2<2>(Qh, Qh, vtv, Oh, Ol, itemp[bh >> 4], bh, qt,
                   threadIdx.x, kbufs, vbufs);
}

// ---------------------------------------------------------------------------
// 3-slice L2-normalize (rows of 64, split in -> split out). In-place safe.
// ---------------------------------------------------------------------------
__device__ __forceinline__ void l2n_body(const unsigned short* ih,
        const unsigned short* il, unsigned short* oh, unsigned short* ol)
{
    size_t row = (size_t)blockIdx.x*4 + (threadIdx.x >> 6);
    int lane = threadIdx.x & 63;
    size_t ii = row*HD + lane;
    float x = bf2f(ih[ii]) + bf2f(il[ii]);
    float s = x*x;
    #pragma unroll
    for (int o = 1; o < 64; o <<= 1) s += __shfl_xor(s, o);
    float xn = x / fmaxf(sqrtf(s), 1e-12f);
    unsigned short hv = f2bf(xn);
    oh[ii] = hv;
    ol[ii] = f2bf(xn - bf2f(hv));
}

__global__ __launch_bounds__(256) void l2n3(
    const unsigned short* __restrict__ i0h, const unsigned short* __restrict__ i0l,
    unsigned short* __restrict__ o0h, unsigned short* __restrict__ o0l,
    const unsigned short* __restrict__ i1h, const unsigned short* __restrict__ i1l,
    unsigned short* __restrict__ o1h, unsigned short* __restrict__ o1l,
    const unsigned short* __restrict__ i2h, const unsigned short* __restrict__ i2l,
    unsigned short* __restrict__ o2h, unsigned short* __restrict__ o2l)
{
    int i = blockIdx.y;
    if (i == 0) l2n_body(i0h, i0l, o0h, o0l);
    else if (i == 1) l2n_body(i1h, i1l, o1h, o1l);
    else l2n_body(i2h, i2l, o2h, o2l);
}

// ---------------------------------------------------------------------------
extern "C" void kernel_launch(void* const* d_in, const int* in_sizes, int n_in,
                              void* d_out, int out_size, void* d_ws, size_t ws_size,
                              hipStream_t stream)
{
    const float* x      = (const float*)d_in[0];
    const float* qkv_w  = (const float*)d_in[1];
    const float* qkv_b  = (const float*)d_in[2];
    const float* proj_w = (const float*)d_in[3];
    const float* proj_b = (const float*)d_in[4];
    float* out = (float*)d_out;            // [0,SZ)=x_gem, [SZ,2SZ)=x_ori

    unsigned short* w16 = (unsigned short*)d_ws;
    #define SL(i) (w16 + (size_t)(i)*SZ)          // 8 bf16 slots
    unsigned short* WQh = w16 + 8*SZ;             // WQ hi, dead after qkv
    unsigned short* VT1 = WQh;                    // aliases WQ
    size_t p = 8*SZ + 2*WSZ;
    unsigned short* VTv = w16 + p;  p += VTSZ;
    unsigned short* VT2 = w16 + p;  p += VTSZ;
    unsigned short* VT3 = w16 + p;  p += VTSZ;
    unsigned short* WPh = w16 + p;  p += PSZ;
    p += PSZ;                                     // layout keep
    unsigned short* E0  = w16 + p;  p += SZ;
    unsigned short* E1  = w16 + p;  p += SZ;
    float* rn = (float*)(w16 + p);  p += 2*(M_ROWS + 8);
    float* it = rn + M_ROWS;
    unsigned short* F0 = w16 + p;  p += SZ;
    unsigned short* F1 = w16 + p;  p += SZ;
    unsigned short* G0 = w16 + p;  p += SZ;
    p += SZ;

    dim3 blk(256);
    dim3 gq(24,37), gt(10,128), gt3(10,128,3), gl3(18464,3);
    dim3 gfl4(640,4), gfl3(640,3), gp2(8,73,2);

    // prologue: merged splits + fused row-norm, inv_temp, qkv gemm, VTv
    split_all<<<dim3(M_ROWS + 4*NC), blk, 0, stream>>>(x, qkv_w, proj_w,
        SL(6), SL(7), WQh, WPh, rn);
    calc_invtemp<<<dim3(NB), blk, 0, stream>>>(rn, it);
    gemm_qkv_mfma<<<gq, blk, 0, stream>>>(SL(6), SL(7), WQh, qkv_b,
        SL(0), SL(1), SL(2), SL(3), SL(4), SL(5));
    transp64<<<gt, blk, 0, stream>>>(SL(4), VTv);

    // xs1 = l2n(v) in-place (4,5); xs2 = l2n(k)->(6,7); xs3 = l2n(q)->E
    l2n3<<<gl3, blk, 0, stream>>>(
        SL(4),SL(5), SL(4),SL(5),
        SL(2),SL(3), SL(6),SL(7),
        SL(0),SL(1), E0,E1);
    transp64x3<<<gt3, blk, 0, stream>>>(SL(4), VT1, SL(6), VT2, E0, VT3);

    // merged: z1->F0, z2->F1, z3->G0 (hi only); o_ori->(SL1,SL3)
    flash4<<<gfl4, blk, 0, stream>>>(
        SL(4), SL(6), E0,
        SL(0), SL(2),
        VT1, VT2, VT3, VTv,
        F0, F1, G0, SL(1), SL(3), it);

    // finals: z x VTv -> (4,5),(6,7),(E0,E1) split
    flashfin<<<gfl3, blk, 0, stream>>>(
        F0, F1, G0, VTv,
        SL(4),SL(5), SL(6),SL(7), E0,E1, it);

    // both projections in one dispatch (independent):
    // z=0: x_gem = proj(sum3/3); z=1: x_ori = proj(o_ori)
    proj2<<<gp2, blk, 0, stream>>>(
        SL(4),SL(5), SL(6),SL(7), E0,E1,
        SL(1),SL(3),
        WPh, proj_b, out, out + SZ);
    #undef SL
}

// Round 22
// 429.728 us; speedup vs baseline: 1.2638x; 1.0574x over previous
//
#include <hip/hip_runtime.h>
#include <math.h>

#define NTOK 577
#define NB 8
#define NC 1024
#define NH 16
#define HD 64
#define M_ROWS (NB*NTOK)               // 4616
#define SZ ((size_t)NB*NH*NTOK*HD)     // 4726784 elements
#define WSZ ((size_t)3*NC*NC)          // 3145728
#define PSZ ((size_t)NC*NC)            // 1048576
#define VTW 608                        // padded key width for VT (19*32)
#define VTSZ ((size_t)NB*NH*HD*VTW)    // 4980736
#define HSTR ((size_t)NTOK*HD)         // 36928 head stride in A-layout
#define LP 36                          // padded LDS row (32 data + 4 pad)
#define LOG2E 1.44269504088896f

typedef __attribute__((ext_vector_type(8)))  short bf16x8_t;
typedef __attribute__((ext_vector_type(8)))  unsigned short u16x8_t;
typedef __attribute__((ext_vector_type(16))) float f32x16_t;

union U4 { unsigned short s[8]; unsigned int u[4]; bf16x8_t v; };

__device__ inline unsigned short f2bf(float x){
    unsigned int u = __float_as_uint(x);
    u = (u + 0x7FFFu + ((u>>16)&1u)) >> 16;
    return (unsigned short)u;
}
__device__ inline float bf2f(unsigned short h){
    return __uint_as_float(((unsigned int)h)<<16);
}
__device__ inline unsigned int cvt_pk(float a, float b){
    unsigned int r;
    asm volatile("v_cvt_pk_bf16_f32 %0, %1, %2" : "=v"(r) : "v"(a), "v"(b));
    return r;
}
__device__ inline float fexp2(float x){
    float r;
    asm("v_exp_f32 %0, %1" : "=v"(r) : "v"(x));
    return r;
}

// ---------------------------------------------------------------------------
// merged split + fused row-norm.
// ---------------------------------------------------------------------------
__global__ __launch_bounds__(256) void split_all(const float* __restrict__ X,
        const float* __restrict__ W, const float* __restrict__ P,
        unsigned short* __restrict__ xh, unsigned short* __restrict__ xl,
        unsigned short* __restrict__ wh, unsigned short* __restrict__ ph,
        float* __restrict__ rn)
{
    int row = blockIdx.x, t = threadIdx.x;
    if (row < M_ROWS){
        int b = row / NTOK, n = row % NTOK;
        const float* s = X + ((size_t)n*NB + b)*NC + 4*t;
        float4 v = *(const float4*)s;
        ushort4 hv, lv;
        hv.x = f2bf(v.x); lv.x = f2bf(v.x - bf2f(hv.x));
        hv.y = f2bf(v.y); lv.y = f2bf(v.y - bf2f(hv.y));
        hv.z = f2bf(v.z); lv.z = f2bf(v.z - bf2f(hv.z));
        hv.w = f2bf(v.w); lv.w = f2bf(v.w - bf2f(hv.w));
        *(ushort4*)(xh + (size_t)row*NC + 4*t) = hv;
        *(ushort4*)(xl + (size_t)row*NC + 4*t) = lv;
        float ss = v.x*v.x + v.y*v.y + v.z*v.z + v.w*v.w;
        #pragma unroll
        for (int o = 1; o < 64; o <<= 1) ss += __shfl_xor(ss, o);
        __shared__ float red[4];
        if ((t & 63) == 0) red[t >> 6] = ss;
        __syncthreads();
        if (t == 0) rn[row] = sqrtf(red[0] + red[1] + red[2] + red[3]);
    } else if (row < M_ROWS + 3*NC){
        size_t drow = row - M_ROWS;
        float4 v = *(const float4*)(W + drow*NC + 4*t);
        ushort4 hv;
        hv.x = f2bf(v.x); hv.y = f2bf(v.y); hv.z = f2bf(v.z); hv.w = f2bf(v.w);
        *(ushort4*)(wh + drow*NC + 4*t) = hv;
    } else {
        size_t drow = row - M_ROWS - 3*NC;
        float4 v = *(const float4*)(P + drow*NC + 4*t);
        ushort4 hv;
        hv.x = f2bf(v.x); hv.y = f2bf(v.y); hv.z = f2bf(v.z); hv.w = f2bf(v.w);
        *(ushort4*)(ph + drow*NC + 4*t) = hv;
    }
}

__global__ __launch_bounds__(256) void calc_invtemp(const float* __restrict__ rn,
                                                    float* __restrict__ it)
{
    int b = blockIdx.x;
    int tid = threadIdx.x;
    float s = 0.f;
    for (int i = tid; i < NTOK; i += 256) s += rn[b*NTOK + i];
    #pragma unroll
    for (int o = 1; o < 64; o <<= 1) s += __shfl_xor(s, o);
    __shared__ float red[4];
    if ((tid & 63) == 0) red[tid >> 6] = s;
    __syncthreads();
    if (tid == 0) it[b] = (red[0]+red[1]+red[2]+red[3]) / (float)NTOK * 0.125f;
}

// ---------------------------------------------------------------------------
// Coalesced transpose: src hi-bf16 [BH][577][64] -> dst [BH][64][608], pads=0.
// ---------------------------------------------------------------------------
__device__ __forceinline__ void transp_body(const unsigned short* src,
                                            unsigned short* dst)
{
    __shared__ unsigned short t[64][72];
    int bh = blockIdx.y;
    int n0 = blockIdx.x * 64;
    int tid = threadIdx.x;
    int r  = tid >> 2;
    int c0 = (tid & 3) * 16;
    int n = n0 + r;
    if (n < NTOK){
        const unsigned short* s = src + ((size_t)bh*NTOK + n)*HD + c0;
        *(u16x8_t*)&t[r][c0]   = *(const u16x8_t*)s;
        *(u16x8_t*)&t[r][c0+8] = *(const u16x8_t*)(s + 8);
    } else {
        u16x8_t z = (u16x8_t)0;
        *(u16x8_t*)&t[r][c0]   = z;
        *(u16x8_t*)&t[r][c0+8] = z;
    }
    __syncthreads();
    if (n0 + c0 < VTW){
        int d = r;
        U4 o0, o1;
        #pragma unroll
        for (int j = 0; j < 8; j++){ o0.s[j] = t[c0+j][d]; o1.s[j] = t[c0+8+j][d]; }
        unsigned short* dp = dst + ((size_t)bh*HD + d)*VTW + n0 + c0;
        *(u16x8_t*)dp       = (u16x8_t)o0.v;
        *(u16x8_t*)(dp + 8) = (u16x8_t)o1.v;
    }
}

__global__ __launch_bounds__(256) void transp64(const unsigned short* __restrict__ src,
                                                unsigned short* __restrict__ dst)
{
    transp_body(src, dst);
}

__global__ __launch_bounds__(256) void transp64x3(
    const unsigned short* __restrict__ s0, unsigned short* __restrict__ d0,
    const unsigned short* __restrict__ s1, unsigned short* __restrict__ d1,
    const unsigned short* __restrict__ s2, unsigned short* __restrict__ d2)
{
    int i = blockIdx.z;
    const unsigned short* s = (i == 0) ? s0 : (i == 1 ? s1 : s2);
    unsigned short* d = (i == 0) ? d0 : (i == 1 ? d1 : d2);
    transp_body(s, d);
}

// A split bf16x2, B hi-only: 8 MFMAs per kk (hh + lh)
#define MFMA8(a0h,a1h,b0,b1,a0l,a1l) \
    acc[0][0] = __builtin_amdgcn_mfma_f32_32x32x16_bf16(a0h, b0, acc[0][0], 0,0,0); \
    acc[0][1] = __builtin_amdgcn_mfma_f32_32x32x16_bf16(a0h, b1, acc[0][1], 0,0,0); \
    acc[1][0] = __builtin_amdgcn_mfma_f32_32x32x16_bf16(a1h, b0, acc[1][0], 0,0,0); \
    acc[1][1] = __builtin_amdgcn_mfma_f32_32x32x16_bf16(a1h, b1, acc[1][1], 0,0,0); \
    acc[0][0] = __builtin_amdgcn_mfma_f32_32x32x16_bf16(a0l, b0, acc[0][0], 0,0,0); \
    acc[0][1] = __builtin_amdgcn_mfma_f32_32x32x16_bf16(a0l, b1, acc[0][1], 0,0,0); \
    acc[1][0] = __builtin_amdgcn_mfma_f32_32x32x16_bf16(a1l, b0, acc[1][0], 0,0,0); \
    acc[1][1] = __builtin_amdgcn_mfma_f32_32x32x16_bf16(a1l, b1, acc[1][1], 0,0,0);

// ---------------------------------------------------------------------------
// qkv GEMM, LDS-staged (128x128 tile, BK=32), XCD-chunked 1D grid (888 blocks).
// ---------------------------------------------------------------------------
__global__ __launch_bounds__(256) void gemm_qkv_mfma(
    const unsigned short* __restrict__ Ah, const unsigned short* __restrict__ Al,
    const unsigned short* __restrict__ Bh,
    const float* __restrict__ bias,
    unsigned short* __restrict__ qh, unsigned short* __restrict__ ql,
    unsigned short* __restrict__ kh, unsigned short* __restrict__ kl,
    unsigned short* __restrict__ vh, unsigned short* __restrict__ vl)
{
    __shared__ unsigned short ahs[128][LP], als[128][LP];
    __shared__ unsigned short bhs[128][LP];
    int t = threadIdx.x;
    int l = t & 63, w = t >> 6;
    int lq = l & 31, hi = l >> 5;
    int wr = w >> 1, wc = w & 1;
    // XCD-chunked swizzle: 888 = 8*111; each XCD gets 111 consecutive work
    // items (col fastest) -> A row-slices L2-resident per XCD.
    int L = blockIdx.x;
    int wk = (L & 7) * 111 + (L >> 3);
    int col0 = (wk % 24) * 128, row0 = (wk / 24) * 128;

    int srow[2], scol[2], sa[2];
    #pragma unroll
    for (int i = 0; i < 2; i++){
        int idx = i*256 + t;
        srow[i] = idx >> 2;
        scol[i] = (idx & 3) * 8;
        int ar = row0 + srow[i]; if (ar >= M_ROWS) ar = M_ROWS-1;
        sa[i] = ar;
    }

    f32x16_t acc[2][2];
    #pragma unroll
    for (int i = 0; i < 16; i++){
        acc[0][0][i]=0.f; acc[0][1][i]=0.f; acc[1][0][i]=0.f; acc[1][1][i]=0.f;
    }

    for (int k0 = 0; k0 < NC; k0 += 32){
        if (k0) __syncthreads();
        #pragma unroll
        for (int i = 0; i < 2; i++){
            size_t ao = (size_t)sa[i]*NC + k0 + scol[i];
            size_t bo = (size_t)(col0 + srow[i])*NC + k0 + scol[i];
            u16x8_t va  = *(const u16x8_t*)(Ah + ao);
            u16x8_t va2 = *(const u16x8_t*)(Al + ao);
            u16x8_t vb  = *(const u16x8_t*)(Bh + bo);
            *(u16x8_t*)&ahs[srow[i]][scol[i]] = va;
            *(u16x8_t*)&als[srow[i]][scol[i]] = va2;
            *(u16x8_t*)&bhs[srow[i]][scol[i]] = vb;
        }
        __syncthreads();
        #pragma unroll
        for (int kk = 0; kk < 2; kk++){
            int co = kk*16 + 8*hi;
            bf16x8_t a0h = *(const bf16x8_t*)&ahs[wr*64+lq][co];
            bf16x8_t a1h = *(const bf16x8_t*)&ahs[wr*64+32+lq][co];
            bf16x8_t b0  = *(const bf16x8_t*)&bhs[wc*64+lq][co];
            bf16x8_t b1  = *(const bf16x8_t*)&bhs[wc*64+32+lq][co];
            bf16x8_t a0l = *(const bf16x8_t*)&als[wr*64+lq][co];
            bf16x8_t a1l = *(const bf16x8_t*)&als[wr*64+32+lq][co];
            MFMA8(a0h,a1h,b0,b1,a0l,a1l)
        }
    }

    int colW = col0 + wc*64, rowW = row0 + wr*64;
    #pragma unroll
    for (int fn = 0; fn < 2; fn++){
        int colb = colW + fn*32 + lq;
        float bb = bias[colb];
        int tt = colb >> 10, h = (colb >> 6) & 15, d = colb & 63;
        unsigned short* dsth = (tt == 0) ? qh : (tt == 1 ? kh : vh);
        unsigned short* dstl = (tt == 0) ? ql : (tt == 1 ? kl : vl);
        #pragma unroll
        for (int fm = 0; fm < 2; fm++){
            #pragma unroll
            for (int r = 0; r < 16; r++){
                int orow = rowW + fm*32 + (r&3) + 8*(r>>2) + 4*hi;
                if (orow < M_ROWS){
                    float val = acc[fm][fn][r] + bb;
                    int b = orow / NTOK, n = orow % NTOK;
                    unsigned short hv = f2bf(val);
                    unsigned short lv = f2bf(val - bf2f(hv));
                    size_t idx = ((size_t)(b*NH + h)*NTOK + n)*HD + d;
                    dsth[idx] = hv; dstl[idx] = lv;
                }
            }
        }
    }
}

// ---------------------------------------------------------------------------
// proj GEMM body, LDS-staged (64x128 tile, BK=32).
// ---------------------------------------------------------------------------
template<int NA>
__device__ __forceinline__ void proj_body(
    const unsigned short* A0h, const unsigned short* A0l,
    const unsigned short* A1h, const unsigned short* A1l,
    const unsigned short* A2h, const unsigned short* A2l,
    const unsigned short* Bh,
    const float* bias, float alpha, float* out, int bx, int by)
{
    __shared__ unsigned short ahs[64][LP], als[64][LP];
    __shared__ unsigned short bhs[128][LP];
    int t = threadIdx.x;
    int l = t & 63, w = t >> 6;
    int lq = l & 31, hi = l >> 5;
    int wr = w >> 1, wc = w & 1;
    int col0 = bx*128, row0 = by*64;

    int sarow = t >> 2, sacol = (t & 3) * 8;
    int ar = row0 + sarow; if (ar >= M_ROWS) ar = M_ROWS-1;
    size_t abase = (size_t)(ar / NTOK)*NH*HSTR + (size_t)(ar % NTOK)*HD;
    int sbrow[2], sbcol[2];
    #pragma unroll
    for (int i = 0; i < 2; i++){
        int idx = i*256 + t;
        sbrow[i] = idx >> 2;
        sbcol[i] = (idx & 3) * 8;
    }

    f32x16_t acc[2];
    #pragma unroll
    for (int i = 0; i < 16; i++){ acc[0][i]=0.f; acc[1][i]=0.f; }

    for (int k0 = 0; k0 < NC; k0 += 32){
        if (k0) __syncthreads();
        {
            int kk = k0 + sacol;
            size_t ao = abase + (size_t)(kk >> 6)*HSTR + (kk & 63);
            U4 h0, l0;
            u16x8_t va  = *(const u16x8_t*)(A0h + ao);
            u16x8_t va2 = *(const u16x8_t*)(A0l + ao);
            if (NA == 3){
                u16x8_t vb  = *(const u16x8_t*)(A1h + ao);
                u16x8_t vb2 = *(const u16x8_t*)(A1l + ao);
                u16x8_t vc  = *(const u16x8_t*)(A2h + ao);
                u16x8_t vc2 = *(const u16x8_t*)(A2l + ao);
                #pragma unroll
                for (int j = 0; j < 8; j++){
                    float s = bf2f(va[j]) + bf2f(va2[j]) + bf2f(vb[j])
                            + bf2f(vb2[j]) + bf2f(vc[j]) + bf2f(vc2[j]);
                    unsigned short hv = f2bf(s);
                    h0.s[j] = hv; l0.s[j] = f2bf(s - bf2f(hv));
                }
                *(u16x8_t*)&ahs[sarow][sacol] = (u16x8_t)h0.v;
                *(u16x8_t*)&als[sarow][sacol] = (u16x8_t)l0.v;
            } else {
                *(u16x8_t*)&ahs[sarow][sacol] = va;
                *(u16x8_t*)&als[sarow][sacol] = va2;
            }
            #pragma unroll
            for (int i = 0; i < 2; i++){
                size_t bo = (size_t)(col0 + sbrow[i])*NC + k0 + sbcol[i];
                u16x8_t vb = *(const u16x8_t*)(Bh + bo);
                *(u16x8_t*)&bhs[sbrow[i]][sbcol[i]] = vb;
            }
        }
        __syncthreads();
        #pragma unroll
        for (int kk = 0; kk < 2; kk++){
            int co = kk*16 + 8*hi;
            bf16x8_t a0h = *(const bf16x8_t*)&ahs[wr*32+lq][co];
            bf16x8_t a0l = *(const bf16x8_t*)&als[wr*32+lq][co];
            bf16x8_t b0  = *(const bf16x8_t*)&bhs[wc*64+lq][co];
            bf16x8_t b1  = *(const bf16x8_t*)&bhs[wc*64+32+lq][co];
            acc[0] = __builtin_amdgcn_mfma_f32_32x32x16_bf16(a0h, b0, acc[0], 0,0,0);
            acc[1] = __builtin_amdgcn_mfma_f32_32x32x16_bf16(a0h, b1, acc[1], 0,0,0);
            acc[0] = __builtin_amdgcn_mfma_f32_32x32x16_bf16(a0l, b0, acc[0], 0,0,0);
            acc[1] = __builtin_amdgcn_mfma_f32_32x32x16_bf16(a0l, b1, acc[1], 0,0,0);
        }
    }

    #pragma unroll
    for (int fn = 0; fn < 2; fn++){
        int colb = col0 + wc*64 + fn*32 + lq;
        float bb = bias[colb];
        #pragma unroll
        for (int r = 0; r < 16; r++){
            int orow = row0 + wr*32 + (r&3) + 8*(r>>2) + 4*hi;
            if (orow < M_ROWS){
                int b = orow / NTOK, n = orow % NTOK;
                out[((size_t)n*NB + b)*NC + colb] = alpha*acc[fn][r] + bb;
            }
        }
    }
}

// 1D XCD-chunked proj: 1168 blocks = 8*146. Work w = (L%8)*146 + L/8;
// w -> z = w/584, by = (w%584)/8, bx = w%8.
__global__ __launch_bounds__(256) void proj2(
    const unsigned short* __restrict__ A0h, const unsigned short* __restrict__ A0l,
    const unsigned short* __restrict__ A1h, const unsigned short* __restrict__ A1l,
    const unsigned short* __restrict__ A2h, const unsigned short* __restrict__ A2l,
    const unsigned short* __restrict__ Oh, const unsigned short* __restrict__ Ol,
    const unsigned short* __restrict__ Bh,
    const float* __restrict__ bias, float* __restrict__ out_gem,
    float* __restrict__ out_ori)
{
    int L = blockIdx.x;
    int wk = (L & 7) * 146 + (L >> 3);
    int z = wk / 584, rem = wk % 584;
    int by = rem >> 3, bx = rem & 7;
    if (z == 0)
        proj_body<3>(A0h,A0l,A1h,A1l,A2h,A2l,Bh,bias,1.f/3.f,out_gem,bx,by);
    else
        proj_body<1>(Oh,Ol,Oh,Ol,Oh,Ol,Bh,bias,1.f,out_ori,bx,by);
}

// ---------------------------------------------------------------------------
// 2-phase LDS-staged flash, 2-kt unroll (pair ping-pong, 1 barrier / 2 kt).
// ---------------------------------------------------------------------------
__device__ __forceinline__ void stage_load(
    const unsigned short* Kh, const unsigned short* VT,
    size_t base, size_t vtb, int kt, int t, u16x8_t& rk, u16x8_t& rv)
{
    int krow = t >> 3, kslot = t & 7;
    int kr = kt*32 + krow; if (kr >= NTOK) kr = NTOK-1;
    rk = *(const u16x8_t*)(Kh + base + (size_t)kr*HD + kslot*8);
    int vrow = t >> 2, vslot = t & 3;
    int vc = kt*32; if (vc > VTW-32) vc = VTW-32;
    rv = *(const u16x8_t*)(VT + vtb + (size_t)vrow*VTW + vc + vslot*8);
}

__device__ __forceinline__ void stage_write(
    unsigned short* kbuf, unsigned short* vbuf, int t,
    const u16x8_t rk, const u16x8_t rv)
{
    int krow = t >> 3, kslot = t & 7;
    int kb = krow*128 + ((kslot*16) ^ ((krow & 7) << 4));
    *(u16x8_t*)((char*)kbuf + kb) = rk;
    int vrow = t >> 2, vslot = t & 3;
    int vb = vrow*64 + ((vslot*16) ^ ((vrow & 3) << 4));
    *(u16x8_t*)((char*)vbuf + vb) = rv;
}

// per-kt compute on a staged tile
template<int VAR>
__device__ __forceinline__ void flash_tile(
    const unsigned short* kbuf, const unsigned short* vbuf,
    int kt, const bf16x8_t* qfh, float l2s, int hi, int lq,
    f32x16_t& od0, f32x16_t& od1, float& m_, float& l_)
{
    const char* kb = (const char*)kbuf;
    const char* vb = (const char*)vbuf;
    bf16x8_t kfh[4];
    #pragma unroll
    for (int c = 0; c < 4; c++)
        kfh[c] = *(const bf16x8_t*)(kb + lq*128 +
                    ((32*c + 16*hi) ^ ((lq & 7) << 4)));
    f32x16_t sf;
    #pragma unroll
    for (int r = 0; r < 16; r++) sf[r] = 0.f;
    __builtin_amdgcn_s_setprio(1);
    #pragma unroll
    for (int c = 0; c < 4; c++)
        sf = __builtin_amdgcn_mfma_f32_32x32x16_bf16(kfh[c], qfh[c], sf, 0,0,0);
    __builtin_amdgcn_s_setprio(0);

    float p[16];
    if (VAR == 0){
        float tm = -1e30f;
        if (kt == 18){
            #pragma unroll
            for (int r = 0; r < 16; r++){
                int key = 576 + (r&3) + 8*(r>>2) + 4*hi;
                p[r] = (key < NTOK) ? sf[r]*l2s : -1e30f;
                tm = fmaxf(tm, p[r]);
            }
        } else {
            #pragma unroll
            for (int r = 0; r < 16; r++){ p[r] = sf[r]*l2s; tm = fmaxf(tm, p[r]); }
        }
        tm = fmaxf(tm, __shfl_xor(tm, 32));
        if (!__all(tm <= m_ + 8.f)){
            float mn = fmaxf(m_, tm);
            float corr = fexp2(m_ - mn);
            l_ *= corr;
            m_ = mn;
            #pragma unroll
            for (int r = 0; r < 16; r++){
                int crow = (r&3) + 8*(r>>2) + 4*hi;
                float cR = __shfl(corr, crow);
                od0[r] *= cR; od1[r] *= cR;
            }
        }
        float ps = 0.f;
        #pragma unroll
        for (int r = 0; r < 16; r++){ p[r] = fexp2(p[r] - m_); ps += p[r]; }
        ps += __shfl_xor(ps, 32);
        l_ += ps;
    } else {
        if (kt == 18){
            #pragma unroll
            for (int r = 0; r < 16; r++){
                int key = 576 + (r&3) + 8*(r>>2) + 4*hi;
                p[r] = (key < NTOK) ? fexp2(sf[r]*l2s - l2s) : 0.f;
            }
        } else {
            #pragma unroll
            for (int r = 0; r < 16; r++) p[r] = fexp2(sf[r]*l2s - l2s);
        }
        if (VAR == 2){
            #pragma unroll
            for (int r = 0; r < 16; r++) l_ += p[r];
        }
    }

    U4 pa[2];
    #pragma unroll
    for (int ks = 0; ks < 2; ks++){
        unsigned int X0 = cvt_pk(p[8*ks+0], p[8*ks+1]);
        unsigned int X1 = cvt_pk(p[8*ks+2], p[8*ks+3]);
        unsigned int X2 = cvt_pk(p[8*ks+4], p[8*ks+5]);
        unsigned int X3 = cvt_pk(p[8*ks+6], p[8*ks+7]);
        unsigned int Y0 = (unsigned int)__shfl_xor((int)X2, 32);
        unsigned int Y1 = (unsigned int)__shfl_xor((int)X3, 32);
        unsigned int Y2 = (unsigned int)__shfl_xor((int)X0, 32);
        unsigned int Y3 = (unsigned int)__shfl_xor((int)X1, 32);
        pa[ks].u[0] = hi ? Y0 : X0;
        pa[ks].u[1] = hi ? Y1 : X1;
        pa[ks].u[2] = hi ? X2 : Y2;
        pa[ks].u[3] = hi ? X3 : Y3;
    }
    int vsw = (lq & 3) << 4;
    bf16x8_t vf00 = *(const bf16x8_t*)(vb + lq*64      + ((16*hi)      ^ vsw));
    bf16x8_t vf01 = *(const bf16x8_t*)(vb + lq*64      + ((32 + 16*hi) ^ vsw));
    bf16x8_t vf10 = *(const bf16x8_t*)(vb + (32+lq)*64 + ((16*hi)      ^ vsw));
    bf16x8_t vf11 = *(const bf16x8_t*)(vb + (32+lq)*64 + ((32 + 16*hi) ^ vsw));
    __builtin_amdgcn_s_setprio(1);
    od0 = __builtin_amdgcn_mfma_f32_32x32x16_bf16(pa[0].v, vf00, od0, 0,0,0);
    od0 = __builtin_amdgcn_mfma_f32_32x32x16_bf16(pa[1].v, vf01, od0, 0,0,0);
    od1 = __builtin_amdgcn_mfma_f32_32x32x16_bf16(pa[0].v, vf10, od1, 0,0,0);
    od1 = __builtin_amdgcn_mfma_f32_32x32x16_bf16(pa[1].v, vf11, od1, 0,0,0);
    __builtin_amdgcn_s_setprio(0);
}

template<int VAR>
__device__ __forceinline__ void flash_body2(
    const unsigned short* Qh, const unsigned short* Kh,
    const unsigned short* VT,
    unsigned short* Ohi, unsigned short* Olo,
    float scale, int bh, int qt, int tid,
    unsigned short (*kbufs)[2][2048], unsigned short (*vbufs)[2][2048])
{
    int lane = tid & 63;
    int hi = lane >> 5, lq = lane & 31;
    const size_t base = (size_t)bh * NTOK * HD;
    const size_t vtb  = (size_t)bh * HD * VTW;
    const float l2s = scale * LOG2E;

    int qrow = qt*32 + lq;
    int qr = qrow < NTOK ? qrow : NTOK-1;
    const size_t qoff = base + (size_t)qr*HD + 8*hi;
    bf16x8_t qfh[4];
    #pragma unroll
    for (int c = 0; c < 4; c++)
        qfh[c] = *(const bf16x8_t*)(Qh + qoff + 16*c);

    f32x16_t od0, od1;
    #pragma unroll
    for (int r = 0; r < 16; r++){ od0[r]=0.f; od1[r]=0.f; }
    float m_ = -1e30f, l_ = 0.f;

    u16x8_t rk0, rv0, rk1, rv1;
    stage_load(Kh, VT, base, vtb, 0, tid, rk0, rv0);
    stage_load(Kh, VT, base, vtb, 1, tid, rk1, rv1);
    stage_write(kbufs[0][0], vbufs[0][0], tid, rk0, rv0);
    stage_write(kbufs[0][1], vbufs[0][1], tid, rk1, rv1);
    __syncthreads();
    int cur = 0;

    for (int i = 0; i < 10; i++){
        int kt0 = 2*i;
        if (i < 9){
            stage_load(Kh, VT, base, vtb, kt0+2, tid, rk0, rv0);
            stage_load(Kh, VT, base, vtb, kt0+3, tid, rk1, rv1);
        }
        flash_tile<VAR>(kbufs[cur][0], vbufs[cur][0], kt0, qfh, l2s, hi, lq,
                        od0, od1, m_, l_);
        if (i < 9){
            stage_write(kbufs[cur^1][0], vbufs[cur^1][0], tid, rk0, rv0);
            stage_write(kbufs[cur^1][1], vbufs[cur^1][1], tid, rk1, rv1);
        }
        if (kt0 + 1 < 19)
            flash_tile<VAR>(kbufs[cur][1], vbufs[cur][1], kt0+1, qfh, l2s, hi, lq,
                            od0, od1, m_, l_);
        __syncthreads();
        cur ^= 1;
    }

    if (VAR == 1){
        #pragma unroll
        for (int r = 0; r < 16; r++){
            float s = od0[r]*od0[r] + od1[r]*od1[r];
            #pragma unroll
            for (int o = 1; o < 32; o <<= 1) s += __shfl_xor(s, o);
            int crow = (r&3) + 8*(r>>2) + 4*hi;
            int qg = qt*32 + crow;
            if (qg < NTOK){
                float inv = 1.f / fmaxf(sqrtf(s), 1e-12f);
                size_t o0 = base + (size_t)qg*HD + lq;
                Ohi[o0]    = f2bf(od0[r]*inv);
                Ohi[o0+32] = f2bf(od1[r]*inv);
            }
        }
        return;
    }

    if (VAR == 2) l_ = l_ + __shfl_xor(l_, 32);
    float linv = 1.f / l_;
    #pragma unroll
    for (int r = 0; r < 16; r++){
        int crow = (r&3) + 8*(r>>2) + 4*hi;
        int qg = qt*32 + crow;
        float li = __shfl(linv, crow);
        if (qg < NTOK){
            size_t o0 = base + (size_t)qg*HD + lq;
            float a0 = od0[r]*li, a1 = od1[r]*li;
            unsigned short h0 = f2bf(a0), h1 = f2bf(a1);
            Ohi[o0] = h0;    Olo[o0]    = f2bf(a0 - bf2f(h0));
            Ohi[o0+32] = h1; Olo[o0+32] = f2bf(a1 - bf2f(h1));
        }
    }
}

// 4-wide merged ys+ori: slices 0-2 = ys_i (VAR=1, fused l2n, hi out);
// slice 3 = x_ori (VAR=0) -> o_ori split pair.
__global__ __launch_bounds__(256) void flash4(
    const unsigned short* __restrict__ x1h,
    const unsigned short* __restrict__ x2h,
    const unsigned short* __restrict__ x3h,
    const unsigned short* __restrict__ qh_,
    const unsigned short* __restrict__ kh_,
    const unsigned short* __restrict__ vt1, const unsigned short* __restrict__ vt2,
    const unsigned short* __restrict__ vt3, const unsigned short* __restrict__ vtv,
    unsigned short* __restrict__ z1h,
    unsigned short* __restrict__ z2h,
    unsigned short* __restrict__ z3h,
    unsigned short* __restrict__ ooh, unsigned short* __restrict__ ool,
    const float* __restrict__ itemp)
{
    __shared__ unsigned short kbufs[2][2][2048], vbufs[2][2][2048];
    int bid = blockIdx.x;
    int bh = (bid & 7) * 16 + (bid >> 3) / 5;
    int w = threadIdx.x >> 6;
    int qt = ((bid >> 3) % 5) * 4 + w; if (qt > 18) qt = 18;
    int i = blockIdx.y;
    if (i == 3){
        flash_body2<0>(qh_, kh_, vtv, ooh, ool, 0.125f, bh, qt,
                       threadIdx.x, kbufs, vbufs);
    } else {
        const unsigned short *Qh, *VT;
        unsigned short *Oh;
        if (i == 0){ Qh=x1h; VT=vt1; Oh=z1h; }
        else if (i == 1){ Qh=x2h; VT=vt2; Oh=z2h; }
        else { Qh=x3h; VT=vt3; Oh=z3h; }
        flash_body2<1>(Qh, Qh, VT, Oh, nullptr, itemp[bh >> 4], bh, qt,
                       threadIdx.x, kbufs, vbufs);
    }
}

// finals (3 slices, VAR=2)
__global__ __launch_bounds__(256) void flashfin(
    const unsigned short* __restrict__ z1h,
    const unsigned short* __restrict__ z2h,
    const unsigned short* __restrict__ z3h,
    const unsigned short* __restrict__ vtv,
    unsigned short* __restrict__ o0h, unsigned short* __restrict__ o0l,
    unsigned short* __restrict__ o1h, unsigned short* __restrict__ o1l,
    unsigned short* __restrict__ o2h, unsigned short* __restrict__ o2l,
    const float* __restrict__ itemp)
{
    __shared__ unsigned short kbufs[2][2][2048], vbufs[2][2][2048];
    int bid = blockIdx.x;
    int bh = (bid & 7) * 16 + (bid >> 3) / 5;
    int w = threadIdx.x >> 6;
    int qt = ((bid >> 3) % 5) * 4 + w; if (qt > 18) qt = 18;
    int i = blockIdx.y;
    const unsigned short* Qh;
    unsigned short *Oh, *Ol;
    if (i == 0){ Qh=z1h; Oh=o0h; Ol=o0l; }
    else if (i == 1){ Qh=z2h; Oh=o1h; Ol=o1l; }
    else { Qh=z3h; Oh=o2h; Ol=o2l; }
    flash_body2<2>(Qh, Qh, vtv, Oh, Ol, itemp[bh >> 4], bh, qt,
                   threadIdx.x, kbufs, vbufs);
}

// ---------------------------------------------------------------------------
// 3-slice L2-normalize (rows of 64, split in -> split out). In-place safe.
// ---------------------------------------------------------------------------
__device__ __forceinline__ void l2n_body(const unsigned short* ih,
        const unsigned short* il, unsigned short* oh, unsigned short* ol)
{
    size_t row = (size_t)blockIdx.x*4 + (threadIdx.x >> 6);
    int lane = threadIdx.x & 63;
    size_t ii = row*HD + lane;
    float x = bf2f(ih[ii]) + bf2f(il[ii]);
    float s = x*x;
    #pragma unroll
    for (int o = 1; o < 64; o <<= 1) s += __shfl_xor(s, o);
    float xn = x / fmaxf(sqrtf(s), 1e-12f);
    unsigned short hv = f2bf(xn);
    oh[ii] = hv;
    ol[ii] = f2bf(xn - bf2f(hv));
}

__global__ __launch_bounds__(256) void l2n3(
    const unsigned short* __restrict__ i0h, const unsigned short* __restrict__ i0l,
    unsigned short* __restrict__ o0h, unsigned short* __restrict__ o0l,
    const unsigned short* __restrict__ i1h, const unsigned short* __restrict__ i1l,
    unsigned short* __restrict__ o1h, unsigned short* __restrict__ o1l,
    const unsigned short* __restrict__ i2h, const unsigned short* __restrict__ i2l,
    unsigned short* __restrict__ o2h, unsigned short* __restrict__ o2l)
{
    int i = blockIdx.y;
    if (i == 0) l2n_body(i0h, i0l, o0h, o0l);
    else if (i == 1) l2n_body(i1h, i1l, o1h, o1l);
    else l2n_body(i2h, i2l, o2h, o2l);
}

// ---------------------------------------------------------------------------
extern "C" void kernel_launch(void* const* d_in, const int* in_sizes, int n_in,
                              void* d_out, int out_size, void* d_ws, size_t ws_size,
                              hipStream_t stream)
{
    const float* x      = (const float*)d_in[0];
    const float* qkv_w  = (const float*)d_in[1];
    const float* qkv_b  = (const float*)d_in[2];
    const float* proj_w = (const float*)d_in[3];
    const float* proj_b = (const float*)d_in[4];
    float* out = (float*)d_out;            // [0,SZ)=x_gem, [SZ,2SZ)=x_ori

    unsigned short* w16 = (unsigned short*)d_ws;
    #define SL(i) (w16 + (size_t)(i)*SZ)          // 8 bf16 slots
    unsigned short* WQh = w16 + 8*SZ;             // WQ hi, dead after qkv
    unsigned short* VT1 = WQh;                    // aliases WQ
    size_t p = 8*SZ + 2*WSZ;
    unsigned short* VTv = w16 + p;  p += VTSZ;
    unsigned short* VT2 = w16 + p;  p += VTSZ;
    unsigned short* VT3 = w16 + p;  p += VTSZ;
    unsigned short* WPh = w16 + p;  p += PSZ;
    p += PSZ;                                     // layout keep
    unsigned short* E0  = w16 + p;  p += SZ;
    unsigned short* E1  = w16 + p;  p += SZ;
    float* rn = (float*)(w16 + p);  p += 2*(M_ROWS + 8);
    float* it = rn + M_ROWS;
    unsigned short* F0 = w16 + p;  p += SZ;
    unsigned short* F1 = w16 + p;  p += SZ;
    unsigned short* G0 = w16 + p;  p += SZ;
    p += SZ;

    dim3 blk(256);
    dim3 gt(10,128), gt3(10,128,3), gl3(18464,3);
    dim3 gfl4(640,4), gfl3(640,3);

    // prologue: merged splits + fused row-norm, inv_temp, qkv gemm, VTv
    split_all<<<dim3(M_ROWS + 4*NC), blk, 0, stream>>>(x, qkv_w, proj_w,
        SL(6), SL(7), WQh, WPh, rn);
    calc_invtemp<<<dim3(NB), blk, 0, stream>>>(rn, it);
    gemm_qkv_mfma<<<dim3(888), blk, 0, stream>>>(SL(6), SL(7), WQh, qkv_b,
        SL(0), SL(1), SL(2), SL(3), SL(4), SL(5));
    transp64<<<gt, blk, 0, stream>>>(SL(4), VTv);

    // xs1 = l2n(v) in-place (4,5); xs2 = l2n(k)->(6,7); xs3 = l2n(q)->E
    l2n3<<<gl3, blk, 0, stream>>>(
        SL(4),SL(5), SL(4),SL(5),
        SL(2),SL(3), SL(6),SL(7),
        SL(0),SL(1), E0,E1);
    transp64x3<<<gt3, blk, 0, stream>>>(SL(4), VT1, SL(6), VT2, E0, VT3);

    // merged: z1->F0, z2->F1, z3->G0 (hi only); o_ori->(SL1,SL3)
    flash4<<<gfl4, blk, 0, stream>>>(
        SL(4), SL(6), E0,
        SL(0), SL(2),
        VT1, VT2, VT3, VTv,
        F0, F1, G0, SL(1), SL(3), it);

    // finals: z x VTv -> (4,5),(6,7),(E0,E1) split
    flashfin<<<gfl3, blk, 0, stream>>>(
        F0, F1, G0, VTv,
        SL(4),SL(5), SL(6),SL(7), E0,E1, it);

    // both projections, XCD-chunked 1D grid (1168 = 8*146):
    // z=0: x_gem = proj(sum3/3); z=1: x_ori = proj(o_ori)
    proj2<<<dim3(1168), blk, 0, stream>>>(
        SL(4),SL(5), SL(6),SL(7), E0,E1,
        SL(1),SL(3),
        WPh, proj_b, out, out + SZ);
    #undef SL
}